// Round 14
// baseline (1244.788 us; speedup 1.0000x reference)
//
#include <hip/hip_runtime.h>
#include <hip/hip_bf16.h>

typedef unsigned int  u32;
typedef unsigned short u16;
typedef unsigned long long u64;
typedef __attribute__((ext_vector_type(8))) short bf16x8;
typedef __attribute__((ext_vector_type(4))) float f32x4;

#define B_   1024
#define T_   128
#define NBT  (B_*T_)
#define CHUNK 32768
#define NCHUNK 4

// ---- wsb (u16 element offsets) ----
#define WG_OFF   0
#define WT_OFF   286720
#define WIH_OFF  311296
#define W2_OFF   376832
#define W1C_OFF  381952
#define CVT_TOTAL 382464

// ---- d_ws byte offsets ----
#define TRUNK_OFF (1ull<<20)
#define H_OFF     (36ull<<20)
#define CTX_OFF   (72ull<<20)
#define C2_OFF    (92ull<<20)
#define GX_OFF    C2_OFF

__device__ __forceinline__ u16 f2bf(float f){
  u32 u = __float_as_uint(f);
  u32 r = u + 0x7fffu + ((u >> 16) & 1u);
  return (u16)(r >> 16);
}
__device__ __forceinline__ float bf2f(u16 u){ return __uint_as_float((u32)u << 16); }
__device__ __forceinline__ float sigm(float x){ return 1.f / (1.f + __expf(-x)); }
__device__ __forceinline__ float tanh_f(float x){ return 2.f / (1.f + __expf(-2.f*x)) - 1.f; }

__device__ __forceinline__ void bar_lds() {
  __builtin_amdgcn_sched_barrier(0);
  asm volatile("s_waitcnt lgkmcnt(0)" ::: "memory");
  __builtin_amdgcn_s_barrier();
  __builtin_amdgcn_sched_barrier(0);
}

// ---------------------------------------------------------------------------
// K0 (verbatim)
// ---------------------------------------------------------------------------
__global__ void k_cvt(const float* __restrict__ gfw, const float* __restrict__ tw,
                      const float* __restrict__ wih, const float* __restrict__ c2w,
                      const float* __restrict__ c1w, u16* __restrict__ wsb) {
  int i = blockIdx.x * 256 + threadIdx.x;
  if (i >= CVT_TOTAL) return;
  float v;
  if (i < WT_OFF) {
    int o = i / 2240; int k = i - o*2240;
    int pos = k >> 5, ch = k & 31;
    v = gfw[o*2240 + ch*70 + pos];
  }
  else if (i < WIH_OFF)  v = tw[i - WT_OFF];
  else if (i < W2_OFF)   v = wih[i - WIH_OFF];
  else if (i < W1C_OFF) {
    int j = i - W2_OFF; int co = j / 160; int k = j - co*160;
    int tap = k >> 4; int ci = k & 15;
    v = (tap < 9) ? c2w[co*144 + ci*9 + tap] : 0.f;
  } else {
    int j = i - W1C_OFF; int ch = j >> 5; int k = j & 31;
    v = (k < 9) ? c1w[ch*9 + k] : 0.f;
  }
  wsb[i] = f2bf(v);
}

// ---------------------------------------------------------------------------
// K1a v2: conv1 + conv2 + ctx_fc. 32 samples/block in 4 groups of 8:
// weight frags / cfw stage / halo zero paid ONCE per block; per-group states
// register-prefetched during compute, parked behind double bar_lds.
// ---------------------------------------------------------------------------
__global__ __launch_bounds__(512, 4) void k_conv(
    const float* __restrict__ states,
    const float* __restrict__ c1b, const float* __restrict__ c2b,
    const float* __restrict__ cfw, const float* __restrict__ cfb,
    const u16* __restrict__ wsb,
    u16* __restrict__ c2g,
    u16* __restrict__ ctxg)
{
  __shared__ float s_st[8][96];
  __shared__ __align__(16) u16 act1[8*108*16];
  __shared__ float s_cf[64][25];

  const int tid  = threadIdx.x;
  const int lane = tid & 63;
  const int w    = tid >> 6;
  const int arow = lane & 15;
  const int grp  = lane >> 4;
  const int g0   = blockIdx.x * 32;   // 4 groups of 8 samples

  bf16x8 Bc1 = *(const bf16x8*)(wsb + W1C_OFF + arow*32 + grp*8);
  bf16x8 b2f[5][2];
  #pragma unroll
  for (int p = 0; p < 5; p++)
    #pragma unroll
    for (int nt = 0; nt < 2; nt++)
      b2f[p][nt] = *(const bf16x8*)(wsb + W2_OFF + (nt*16 + arow)*160 + p*32 + grp*8);
  float c1bv[4], c2bv0[4], c2bv1[4];
  #pragma unroll
  for (int r = 0; r < 4; r++) {
    c1bv[r]  = c1b[grp*4 + r];
    c2bv0[r] = c2b[grp*4 + r];
    c2bv1[r] = c2b[16 + grp*4 + r];
  }
  const float cfbr = cfb[lane];
  const int sst_s = (tid*2)/94, sst_c = (tid*2)%94;

  // one-time staging: states(group0), halo zero, cfw
  if (tid < 376) {
    float2 v = *(const float2*)(states + (size_t)g0*94 + tid*2);
    *(float2*)&s_st[sst_s][sst_c] = v;
  }
  for (int i = tid; i < 608; i += 512) {
    int s = i / 76; int r = i - s*76; int hi2 = r >> 1; int h = r & 1;
    int hp;
    if (hi2 < 12)      hp = hi2;
    else if (hi2 < 24) hp = 96 + (hi2 - 12);
    else if (hi2 < 31) hp = (hi2 - 23) * 12;
    else               hp = (hi2 - 30) * 12 + 11;
    u32 a = (u32)((s*108 + hp)*32 + h*16) ^ (u32)((hp & 7) << 4);
    *(uint4*)((char*)act1 + a) = (uint4){0,0,0,0};
  }
  for (int i = tid; i < 1536; i += 512) s_cf[i/24][i%24] = cfw[i];
  bar_lds();

  const bf16x8 zv = {0,0,0,0,0,0,0,0};

  for (int g = 0; g < 4; g++) {
    const int m0 = g0 + g*8;
    float2 npre;
    const bool haspre = (g < 3) && (tid < 376);
    if (haspre)
      npre = *(const float2*)(states + (size_t)(m0 + 8)*94 + tid*2);

    // ---- conv1 MFMA ----
    for (int mt = w; mt < 35; mt += 8) {
      int row = mt*16 + arow;
      int s = (int)(((u32)row * 59919u) >> 22); int pos = row - s*70;
      int y = (int)(((u32)pos * 6554u) >> 16);  int x = pos - y*10;
      bf16x8 pf = zv;
      if (grp == 0) {
        const float* gs = &s_st[s][0];
        #pragma unroll
        for (int t = 0; t < 8; t++) {
          int dy = t/3, dx = t - (t/3)*3;
          int yy = y + dy - 1, xx = x + dx - 1;
          bool ok = (yy >= 0) & (yy < 7) & (xx >= 0) & (xx < 10);
          float v = gs[ok ? yy*10 + xx : 0];
          pf[t] = (short)f2bf(ok ? v : 0.f);
        }
      } else if (grp == 1) {
        int yy = y + 1, xx = x + 1;
        bool ok = (yy < 7) & (xx < 10);
        float v = s_st[s][ok ? yy*10 + xx : 0];
        pf[0] = (short)f2bf(ok ? v : 0.f);
      }
      f32x4 acc = __builtin_amdgcn_mfma_f32_16x16x32_bf16(Bc1, pf, (f32x4){0.f,0.f,0.f,0.f}, 0, 0, 0);
      int hp = (y+1)*12 + (x+1);
      u16 q0 = f2bf(fmaxf(acc[0] + c1bv[0], 0.f));
      u16 q1 = f2bf(fmaxf(acc[1] + c1bv[1], 0.f));
      u16 q2 = f2bf(fmaxf(acc[2] + c1bv[2], 0.f));
      u16 q3 = f2bf(fmaxf(acc[3] + c1bv[3], 0.f));
      u64 pk = (u64)q0 | ((u64)q1 << 16) | ((u64)q2 << 32) | ((u64)q3 << 48);
      u32 wa = (u32)(((s*108 + hp)*16 + grp*4)*2) ^ (u32)((hp & 7) << 4);
      *(u64*)((char*)act1 + wa) = pk;
    }
    bar_lds();

    // ---- conv2 MFMA + ctx ----
    for (int mt = w; mt < 35; mt += 8) {
      int row = mt*16 + arow;
      int s = (int)(((u32)row * 59919u) >> 22); int pos = row - s*70;
      int y = (int)(((u32)pos * 6554u) >> 16);  int x = pos - y*10;
      f32x4 acc0 = {0.f,0.f,0.f,0.f}, acc1 = {0.f,0.f,0.f,0.f};
      #pragma unroll
      for (int p = 0; p < 5; p++) {
        int tap = p*2 + (grp >> 1); if (tap > 8) tap = 8;
        int dy = (tap * 11) >> 5; int dx = tap - dy*3;
        int hp = (y + dy)*12 + (x + dx);
        u32 ra = (u32)(((s*108 + hp)*16 + (grp & 1)*8)*2) ^ (u32)((hp & 7) << 4);
        bf16x8 bv = *(const bf16x8*)((const char*)act1 + ra);
        acc0 = __builtin_amdgcn_mfma_f32_16x16x32_bf16(b2f[p][0], bv, acc0, 0, 0, 0);
        acc1 = __builtin_amdgcn_mfma_f32_16x16x32_bf16(b2f[p][1], bv, acc1, 0, 0, 0);
      }
      {
        u16 q0 = f2bf(fmaxf(acc0[0] + c2bv0[0], 0.f));
        u16 q1 = f2bf(fmaxf(acc0[1] + c2bv0[1], 0.f));
        u16 q2 = f2bf(fmaxf(acc0[2] + c2bv0[2], 0.f));
        u16 q3 = f2bf(fmaxf(acc0[3] + c2bv0[3], 0.f));
        u64 pk = (u64)q0 | ((u64)q1 << 16) | ((u64)q2 << 32) | ((u64)q3 << 48);
        *(u64*)(c2g + (size_t)(m0 + s)*2240 + pos*32 + grp*4) = pk;
      }
      {
        u16 q0 = f2bf(fmaxf(acc1[0] + c2bv1[0], 0.f));
        u16 q1 = f2bf(fmaxf(acc1[1] + c2bv1[1], 0.f));
        u16 q2 = f2bf(fmaxf(acc1[2] + c2bv1[2], 0.f));
        u16 q3 = f2bf(fmaxf(acc1[3] + c2bv1[3], 0.f));
        u64 pk = (u64)q0 | ((u64)q1 << 16) | ((u64)q2 << 32) | ((u64)q3 << 48);
        *(u64*)(c2g + (size_t)(m0 + s)*2240 + pos*32 + 16 + grp*4) = pk;
      }
    }
    {
      float a = cfbr;
      #pragma unroll
      for (int k = 0; k < 24; k++) a = fmaf(s_cf[lane][k], s_st[w][70 + k], a);
      ctxg[(size_t)(m0 + w)*64 + lane] = f2bf(fmaxf(a, 0.f));
    }

    // ---- group end: retire s_st readers, park next states ----
    if (g < 3) {
      bar_lds();
      if (haspre) *(float2*)&s_st[sst_s][sst_c] = npre;
      bar_lds();
    }
  }
}

// ---------------------------------------------------------------------------
// K1b v3: BARRIER-FREE K-loop. B fragments read directly from L2 (573 KB
// weight matrix is L2-resident); 2-deep register pipes on A and B.
// Epilogue (ctx concat + trunk) unchanged from verified v2.
// ---------------------------------------------------------------------------
__global__ __launch_bounds__(512, 2) void k_gemm(
    const u16* __restrict__ c2g, const u16* __restrict__ ctxg,
    const float* __restrict__ gfb, const float* __restrict__ tbv,
    const u16* __restrict__ wsb, u16* __restrict__ trunk_ws, int nbase)
{
  __shared__ __align__(16) u16 s_g[64*204];      // 26.1 KB (epilogue only)

  const int tid  = threadIdx.x;
  const int lane = tid & 63;
  const int w    = tid >> 6;
  const int arow = lane & 15;
  const int grp  = lane >> 4;
  const int wm   = w & 3;
  const int wn   = w >> 2;
  const int m0   = blockIdx.x * 64;

  float gfbv[4], tbvv[4];
  #pragma unroll
  for (int q = 0; q < 4; q++) {
    gfbv[q] = gfb[(wn*4 + q)*16 + arow];
    tbvv[q] = tbv[(wn*4 + q)*16 + arow];
  }

  const u16* ap = c2g + (size_t)(m0 + wm*16 + arow) * 2240 + grp*8;
  const u16* bp[4];
  #pragma unroll
  for (int q = 0; q < 4; q++)
    bp[q] = wsb + WG_OFF + (size_t)((wn*4 + q)*16 + arow)*2240 + grp*8;

  f32x4 acc[4];
  #pragma unroll
  for (int q = 0; q < 4; q++) acc[q] = (f32x4){0.f,0.f,0.f,0.f};

  // 2-deep register pipes (no LDS, no barriers)
  bf16x8 aC = *(const bf16x8*)ap;
  bf16x8 aN = *(const bf16x8*)(ap + 32);
  bf16x8 bC[4], bN[4];
  #pragma unroll
  for (int q = 0; q < 4; q++) {
    bC[q] = *(const bf16x8*)(bp[q]);
    bN[q] = *(const bf16x8*)(bp[q] + 32);
  }

  #pragma unroll 2
  for (int ks = 0; ks < 70; ks++) {
    bf16x8 aF = aN, bF[4];
    #pragma unroll
    for (int q = 0; q < 4; q++) bF[q] = bN[q];
    if (ks < 68) {
      aF = *(const bf16x8*)(ap + (size_t)(ks+2)*32);
      #pragma unroll
      for (int q = 0; q < 4; q++)
        bF[q] = *(const bf16x8*)(bp[q] + (size_t)(ks+2)*32);
    }
    #pragma unroll
    for (int q = 0; q < 4; q++)
      acc[q] = __builtin_amdgcn_mfma_f32_16x16x32_bf16(aC, bC[q], acc[q], 0, 0, 0);
    aC = aN; aN = aF;
    #pragma unroll
    for (int q = 0; q < 4; q++) { bC[q] = bN[q]; bN[q] = bF[q]; }
  }

  // grid_fc -> s_g (wn half) + ctx cols 128..191
  #pragma unroll
  for (int q = 0; q < 4; q++)
    #pragma unroll
    for (int r = 0; r < 4; r++)
      s_g[(wm*16 + grp*4 + r)*204 + (wn*4 + q)*16 + arow] = f2bf(fmaxf(acc[q][r] + gfbv[q], 0.f));
  {
    int row = tid >> 3, seg = (tid & 7) * 8;
    uint4 c0 = *(const uint4*)(ctxg + (size_t)(m0 + row)*64 + seg);
    *(uint4*)&s_g[row*204 + 128 + seg] = c0;
  }
  bar_lds();

  f32x4 tacc[4];
  #pragma unroll
  for (int q = 0; q < 4; q++) tacc[q] = (f32x4){0.f,0.f,0.f,0.f};
  #pragma unroll
  for (int ks = 0; ks < 6; ks++) {
    bf16x8 av = *(const bf16x8*)&s_g[(wm*16 + arow)*204 + ks*32 + grp*8];
    #pragma unroll
    for (int q = 0; q < 4; q++) {
      bf16x8 bv = *(const bf16x8*)(wsb + WT_OFF + (size_t)((wn*4 + q)*16 + arow)*192 + ks*32 + grp*8);
      tacc[q] = __builtin_amdgcn_mfma_f32_16x16x32_bf16(av, bv, tacc[q], 0, 0, 0);
    }
  }
  bar_lds();
  #pragma unroll
  for (int q = 0; q < 4; q++)
    #pragma unroll
    for (int r = 0; r < 4; r++)
      s_g[(wm*16 + grp*4 + r)*204 + (wn*4 + q)*16 + arow] = f2bf(fmaxf(tacc[q][r] + tbvv[q], 0.f));
  bar_lds();

  {
    const int t0 = (nbase + m0) & 127;
    const int bb = (nbase + m0) >> 7;
    int row = tid >> 3, seg = (tid & 7) * 16;
    #pragma unroll
    for (int j = 0; j < 2; j++) {
      uint4 v = *(const uint4*)&s_g[row*204 + seg + j*8];
      *(uint4*)(trunk_ws + ((size_t)(t0 + row)*B_ + bb)*128 + seg + j*8) = v;
    }
  }
}

// ---------------------------------------------------------------------------
// K1c: k_xg (verbatim — [t][b][512]).
// ---------------------------------------------------------------------------
__global__ __launch_bounds__(512, 2) void k_xg(
    const u16* __restrict__ trunk_ws, const u16* __restrict__ wsb,
    u16* __restrict__ gxg)
{
  const int tid  = threadIdx.x;
  const int lane = tid & 63;
  const int w    = tid >> 6;
  const int arow = lane & 15;
  const int grp  = lane >> 4;
  const int t    = blockIdx.x >> 3;
  const int bch  = (blockIdx.x & 7) * 128;
  const int samp = bch + w*16 + arow;

  bf16x8 bv[4];
  #pragma unroll
  for (int ks = 0; ks < 4; ks++)
    bv[ks] = *(const bf16x8*)(trunk_ws + ((size_t)t*B_ + samp)*128 + ks*32 + grp*8);

  const u16* wip = wsb + WIH_OFF;
  u16* gout = gxg + ((size_t)t*B_ + samp)*512;

  #pragma unroll 1
  for (int ntb = 0; ntb < 32; ntb += 4) {
    f32x4 acc[4];
    #pragma unroll
    for (int q = 0; q < 4; q++) acc[q] = (f32x4){0.f,0.f,0.f,0.f};
    #pragma unroll
    for (int ks = 0; ks < 4; ks++) {
      #pragma unroll
      for (int q = 0; q < 4; q++) {
        bf16x8 aw = *(const bf16x8*)(wip + (size_t)((ntb+q)*16 + arow)*128 + ks*32 + grp*8);
        acc[q] = __builtin_amdgcn_mfma_f32_16x16x32_bf16(aw, bv[ks], acc[q], 0, 0, 0);
      }
    }
    #pragma unroll
    for (int q = 0; q < 4; q++) {
      u16 q0 = f2bf(acc[q][0]);
      u16 q1 = f2bf(acc[q][1]);
      u16 q2 = f2bf(acc[q][2]);
      u16 q3 = f2bf(acc[q][3]);
      u64 pk = (u64)q0 | ((u64)q1 << 16) | ((u64)q2 << 32) | ((u64)q3 << 48);
      *(u64*)(gout + (ntb+q)*16 + grp*4) = pk;
    }
  }
}

// ---------------------------------------------------------------------------
// K2: MFMA LSTM v5 (verbatim R13 — at dependency floor).
// ---------------------------------------------------------------------------
__global__ __launch_bounds__(512, 1) void k_lstm(
    const u16* __restrict__ gxg, const float* __restrict__ whh,
    const float* __restrict__ bih, u16* __restrict__ h_ws)
{
  __shared__ __align__(16) u16 s_h[2][16*136];

  const int tid  = threadIdx.x;
  const int lane = tid & 63;
  const int w    = tid >> 6;
  const int arow = lane & 15;
  const int grp  = lane >> 4;
  const int b0   = blockIdx.x * 4;

  bf16x8 Bv[4][4];
  float bihv[4];
  #pragma unroll
  for (int j = 0; j < 4; j++) {
    const int row = j*128 + w*16 + arow;
    bihv[j] = bih[row];
    #pragma unroll
    for (int ks = 0; ks < 4; ks++) {
      const float* s1 = whh + (size_t)row*128 + ks*32 + grp*8;
      float4 a0 = *(const float4*)s1, a1 = *(const float4*)(s1 + 4);
      bf16x8 t1;
      t1[0]=(short)f2bf(a0.x); t1[1]=(short)f2bf(a0.y); t1[2]=(short)f2bf(a0.z); t1[3]=(short)f2bf(a0.w);
      t1[4]=(short)f2bf(a1.x); t1[5]=(short)f2bf(a1.y); t1[6]=(short)f2bf(a1.z); t1[7]=(short)f2bf(a1.w);
      Bv[j][ks] = t1;
    }
  }

  for (int i = tid; i < 2*16*136; i += 512) ((u16*)s_h)[i] = 0;

  const u16* gxb = gxg + ((size_t)(b0 + grp))*512 + w*16 + arow;
  u16 Gc[4], Gn[4];
  #pragma unroll
  for (int j = 0; j < 4; j++) {
    Gc[j] = gxb[(size_t)0*B_*512 + j*128];
    Gn[j] = gxb[(size_t)1*B_*512 + j*128];
  }

  const int prow = tid >> 4, pseg = (tid & 15) * 8;
  float cst = 0.f;
  __syncthreads();

  for (int t = 0; t < T_; t++) {
    const int p = t & 1;

    u16 Gf[4] = {0,0,0,0};
    if (t + 2 < T_) {
      #pragma unroll
      for (int j = 0; j < 4; j++)
        Gf[j] = gxb[(size_t)(t+2)*B_*512 + j*128];
    }
    if (t > 0 && tid < 64) {
      uint4 hv = *(const uint4*)&s_h[p][prow*136 + pseg];
      *(uint4*)(h_ws + ((size_t)(t-1)*B_ + b0 + prow)*128 + pseg) = hv;
    }

    f32x4 racc[4];
    #pragma unroll
    for (int j = 0; j < 4; j++) racc[j] = (f32x4){0.f,0.f,0.f,0.f};
    #pragma unroll
    for (int ks = 0; ks < 4; ks++) {
      bf16x8 av = *(const bf16x8*)&s_h[p][arow*136 + ks*32 + grp*8];
      #pragma unroll
      for (int j = 0; j < 4; j++)
        racc[j] = __builtin_amdgcn_mfma_f32_16x16x32_bf16(av, Bv[j][ks], racc[j], 0, 0, 0);
    }

    float g4[4];
    #pragma unroll
    for (int j = 0; j < 4; j++) {
      float t0v = __shfl(racc[j][0], arow);
      float t1v = __shfl(racc[j][1], arow);
      float t2v = __shfl(racc[j][2], arow);
      float t3v = __shfl(racc[j][3], arow);
      g4[j] = (grp == 0) ? t0v : (grp == 1) ? t1v : (grp == 2) ? t2v : t3v;
    }

    {
      float xi = g4[0] + bf2f(Gc[0]) + bihv[0];
      float xf = g4[1] + bf2f(Gc[1]) + bihv[1];
      float xg = g4[2] + bf2f(Gc[2]) + bihv[2];
      float xo = g4[3] + bf2f(Gc[3]) + bihv[3];
      float I = sigm(xi), F = sigm(xf), O = sigm(xo), G = tanh_f(xg);
      cst = F*cst + I*G;
      float hvv = O * tanh_f(cst);
      s_h[1-p][grp*136 + w*16 + arow] = f2bf(hvv);
    }

    #pragma unroll
    for (int j = 0; j < 4; j++) { Gc[j] = Gn[j]; Gn[j] = Gf[j]; }
    bar_lds();
  }

  if (tid < 64) {
    uint4 hv = *(const uint4*)&s_h[T_ & 1][prow*136 + pseg];
    *(uint4*)(h_ws + ((size_t)(T_-1)*B_ + b0 + prow)*128 + pseg) = hv;
  }
}

// ---------------------------------------------------------------------------
// K3: heads (verbatim).
// ---------------------------------------------------------------------------
__global__ __launch_bounds__(256, 1) void k_heads(
    const u16* __restrict__ h_ws, const int* __restrict__ actions,
    const float* __restrict__ aw, const float* __restrict__ ab,
    const float* __restrict__ cw, const float* __restrict__ cb,
    float* __restrict__ out)
{
  const int tid  = threadIdx.x;
  const int lane = tid & 63;
  const int w    = tid >> 6;
  const int arow = lane & 15;
  const int grp  = lane >> 4;

  bf16x8 Ah[4];
  #pragma unroll
  for (int ks = 0; ks < 4; ks++) {
    bf16x8 v = {0,0,0,0,0,0,0,0};
    if (arow < 4) {
      const float* src = aw + arow*128 + ks*32 + grp*8;
      #pragma unroll
      for (int j = 0; j < 8; j++) v[j] = (short)f2bf(src[j]);
    } else if (arow == 4) {
      const float* src = cw + ks*32 + grp*8;
      #pragma unroll
      for (int j = 0; j < 8; j++) v[j] = (short)f2bf(src[j]);
    }
    Ah[ks] = v;
  }
  const float ab0=ab[0], ab1=ab[1], ab2=ab[2], ab3=ab[3], cb0=cb[0];

  #pragma unroll
  for (int g = 0; g < 4; g++) {
    int m0 = (blockIdx.x*4 + w)*64 + g*16;
    int t  = m0 >> 10; int bb = m0 & 1023;
    f32x4 acc = {0.f,0.f,0.f,0.f};
    #pragma unroll
    for (int ks = 0; ks < 4; ks++) {
      bf16x8 bv = *(const bf16x8*)(h_ws + ((size_t)t*B_ + bb + arow)*128 + ks*32 + grp*8);
      acc = __builtin_amdgcn_mfma_f32_16x16x32_bf16(Ah[ks], bv, acc, 0, 0, 0);
    }
    float cr = __shfl_xor(acc[0], 16);
    if (grp == 0) {
      float L0 = acc[0] + ab0, L1 = acc[1] + ab1, L2 = acc[2] + ab2, L3 = acc[3] + ab3;
      float Lv = cr + cb0;
      float mm = fmaxf(fmaxf(L0, L1), fmaxf(L2, L3));
      float e0 = __expf(L0-mm), e1 = __expf(L1-mm), e2 = __expf(L2-mm), e3 = __expf(L3-mm);
      float S = e0+e1+e2+e3; float lse = __logf(S);
      float p0=L0-mm-lse, p1=L1-mm-lse, p2=L2-mm-lse, p3=L3-mm-lse;
      int n = (bb + arow)*T_ + t;
      int a = actions[n];
      float lpa = (a==0)?p0:(a==1)?p1:(a==2)?p2:p3;
      float ent = -(e0*p0 + e1*p1 + e2*p2 + e3*p3) / S;
      out[n] = lpa; out[NBT + n] = Lv; out[2*NBT + n] = ent;
    }
  }
}

extern "C" void kernel_launch(void* const* d_in, const int* in_sizes, int n_in,
                              void* d_out, int out_size, void* d_ws, size_t ws_size,
                              hipStream_t stream) {
  const float* states = (const float*)d_in[0];
  const int*   actions= (const int*)  d_in[1];
  const float* c1w = (const float*)d_in[2];
  const float* c1b = (const float*)d_in[3];
  const float* c2w = (const float*)d_in[4];
  const float* c2b = (const float*)d_in[5];
  const float* gfw = (const float*)d_in[6];
  const float* gfb = (const float*)d_in[7];
  const float* cfw = (const float*)d_in[8];
  const float* cfb = (const float*)d_in[9];
  const float* tw  = (const float*)d_in[10];
  const float* tbv = (const float*)d_in[11];
  const float* wih = (const float*)d_in[12];
  const float* bih = (const float*)d_in[13];
  const float* whh = (const float*)d_in[14];
  const float* aw  = (const float*)d_in[15];
  const float* ab  = (const float*)d_in[16];
  const float* cw  = (const float*)d_in[17];
  const float* cb  = (const float*)d_in[18];
  float* out = (float*)d_out;

  u16* wsb   = (u16*)d_ws;
  u16* trunk = (u16*)((char*)d_ws + TRUNK_OFF);
  u16* h_ws  = (u16*)((char*)d_ws + H_OFF);
  u16* ctxg  = (u16*)((char*)d_ws + CTX_OFF);
  u16* c2g   = (u16*)((char*)d_ws + C2_OFF);
  u16* gxg   = (u16*)((char*)d_ws + GX_OFF);

  k_cvt<<<(CVT_TOTAL + 255)/256, 256, 0, stream>>>(gfw, tw, wih, c2w, c1w, wsb);

  for (int c = 0; c < NCHUNK; c++) {
    const float* st_c = states + (size_t)c * CHUNK * 94;
    u16* ctx_c = ctxg + (size_t)c * CHUNK * 64;
    k_conv<<<CHUNK/32, 512, 0, stream>>>(st_c, c1b, c2b, cfw, cfb, wsb, c2g, ctx_c);
    k_gemm<<<CHUNK/64, 512, 0, stream>>>(c2g, ctx_c, gfb, tbv, wsb, trunk, c*CHUNK);
  }
  k_xg<<<T_*8, 512, 0, stream>>>(trunk, wsb, gxg);
  k_lstm<<<B_/4, 512, 0, stream>>>(gxg, whh, bih, h_ws);
  k_heads<<<512, 256, 0, stream>>>(h_ws, actions, aw, ab, cw, cb, out);
}

// Round 15
// 803.869 us; speedup vs baseline: 1.5485x; 1.5485x over previous
//
#include <hip/hip_runtime.h>
#include <hip/hip_bf16.h>

typedef unsigned int  u32;
typedef unsigned short u16;
typedef unsigned long long u64;
typedef __attribute__((ext_vector_type(8))) short bf16x8;
typedef __attribute__((ext_vector_type(4))) float f32x4;

#define B_   1024
#define T_   128
#define NBT  (B_*T_)
#define CHUNK 32768
#define NCHUNK 4

// ---- wsb (u16 element offsets) ----
#define WG_OFF   0
#define WT_OFF   286720
#define WIH_OFF  311296
#define W2_OFF   376832
#define W1C_OFF  381952
#define CVT_TOTAL 382464

// ---- d_ws byte offsets ----
#define TRUNK_OFF (1ull<<20)
#define H_OFF     (36ull<<20)
#define CTX_OFF   (72ull<<20)
#define C2_OFF    (92ull<<20)
#define GX_OFF    C2_OFF

__device__ __forceinline__ u16 f2bf(float f){
  u32 u = __float_as_uint(f);
  u32 r = u + 0x7fffu + ((u >> 16) & 1u);
  return (u16)(r >> 16);
}
__device__ __forceinline__ float bf2f(u16 u){ return __uint_as_float((u32)u << 16); }
__device__ __forceinline__ float sigm(float x){ return 1.f / (1.f + __expf(-x)); }
__device__ __forceinline__ float tanh_f(float x){ return 2.f / (1.f + __expf(-2.f*x)) - 1.f; }

__device__ __forceinline__ void bar_lds() {
  __builtin_amdgcn_sched_barrier(0);
  asm volatile("s_waitcnt lgkmcnt(0)" ::: "memory");
  __builtin_amdgcn_s_barrier();
  __builtin_amdgcn_sched_barrier(0);
}

// ---------------------------------------------------------------------------
// K0 (verbatim)
// ---------------------------------------------------------------------------
__global__ void k_cvt(const float* __restrict__ gfw, const float* __restrict__ tw,
                      const float* __restrict__ wih, const float* __restrict__ c2w,
                      const float* __restrict__ c1w, u16* __restrict__ wsb) {
  int i = blockIdx.x * 256 + threadIdx.x;
  if (i >= CVT_TOTAL) return;
  float v;
  if (i < WT_OFF) {
    int o = i / 2240; int k = i - o*2240;
    int pos = k >> 5, ch = k & 31;
    v = gfw[o*2240 + ch*70 + pos];
  }
  else if (i < WIH_OFF)  v = tw[i - WT_OFF];
  else if (i < W2_OFF)   v = wih[i - WIH_OFF];
  else if (i < W1C_OFF) {
    int j = i - W2_OFF; int co = j / 160; int k = j - co*160;
    int tap = k >> 4; int ci = k & 15;
    v = (tap < 9) ? c2w[co*144 + ci*9 + tap] : 0.f;
  } else {
    int j = i - W1C_OFF; int ch = j >> 5; int k = j & 31;
    v = (k < 9) ? c1w[ch*9 + k] : 0.f;
  }
  wsb[i] = f2bf(v);
}

// ---------------------------------------------------------------------------
// K1a v2: conv (verbatim R14 — WON, keep).
// ---------------------------------------------------------------------------
__global__ __launch_bounds__(512, 4) void k_conv(
    const float* __restrict__ states,
    const float* __restrict__ c1b, const float* __restrict__ c2b,
    const float* __restrict__ cfw, const float* __restrict__ cfb,
    const u16* __restrict__ wsb,
    u16* __restrict__ c2g,
    u16* __restrict__ ctxg)
{
  __shared__ float s_st[8][96];
  __shared__ __align__(16) u16 act1[8*108*16];
  __shared__ float s_cf[64][25];

  const int tid  = threadIdx.x;
  const int lane = tid & 63;
  const int w    = tid >> 6;
  const int arow = lane & 15;
  const int grp  = lane >> 4;
  const int g0   = blockIdx.x * 32;

  bf16x8 Bc1 = *(const bf16x8*)(wsb + W1C_OFF + arow*32 + grp*8);
  bf16x8 b2f[5][2];
  #pragma unroll
  for (int p = 0; p < 5; p++)
    #pragma unroll
    for (int nt = 0; nt < 2; nt++)
      b2f[p][nt] = *(const bf16x8*)(wsb + W2_OFF + (nt*16 + arow)*160 + p*32 + grp*8);
  float c1bv[4], c2bv0[4], c2bv1[4];
  #pragma unroll
  for (int r = 0; r < 4; r++) {
    c1bv[r]  = c1b[grp*4 + r];
    c2bv0[r] = c2b[grp*4 + r];
    c2bv1[r] = c2b[16 + grp*4 + r];
  }
  const float cfbr = cfb[lane];
  const int sst_s = (tid*2)/94, sst_c = (tid*2)%94;

  if (tid < 376) {
    float2 v = *(const float2*)(states + (size_t)g0*94 + tid*2);
    *(float2*)&s_st[sst_s][sst_c] = v;
  }
  for (int i = tid; i < 608; i += 512) {
    int s = i / 76; int r = i - s*76; int hi2 = r >> 1; int h = r & 1;
    int hp;
    if (hi2 < 12)      hp = hi2;
    else if (hi2 < 24) hp = 96 + (hi2 - 12);
    else if (hi2 < 31) hp = (hi2 - 23) * 12;
    else               hp = (hi2 - 30) * 12 + 11;
    u32 a = (u32)((s*108 + hp)*32 + h*16) ^ (u32)((hp & 7) << 4);
    *(uint4*)((char*)act1 + a) = (uint4){0,0,0,0};
  }
  for (int i = tid; i < 1536; i += 512) s_cf[i/24][i%24] = cfw[i];
  bar_lds();

  const bf16x8 zv = {0,0,0,0,0,0,0,0};

  for (int g = 0; g < 4; g++) {
    const int m0 = g0 + g*8;
    float2 npre;
    const bool haspre = (g < 3) && (tid < 376);
    if (haspre)
      npre = *(const float2*)(states + (size_t)(m0 + 8)*94 + tid*2);

    for (int mt = w; mt < 35; mt += 8) {
      int row = mt*16 + arow;
      int s = (int)(((u32)row * 59919u) >> 22); int pos = row - s*70;
      int y = (int)(((u32)pos * 6554u) >> 16);  int x = pos - y*10;
      bf16x8 pf = zv;
      if (grp == 0) {
        const float* gs = &s_st[s][0];
        #pragma unroll
        for (int t = 0; t < 8; t++) {
          int dy = t/3, dx = t - (t/3)*3;
          int yy = y + dy - 1, xx = x + dx - 1;
          bool ok = (yy >= 0) & (yy < 7) & (xx >= 0) & (xx < 10);
          float v = gs[ok ? yy*10 + xx : 0];
          pf[t] = (short)f2bf(ok ? v : 0.f);
        }
      } else if (grp == 1) {
        int yy = y + 1, xx = x + 1;
        bool ok = (yy < 7) & (xx < 10);
        float v = s_st[s][ok ? yy*10 + xx : 0];
        pf[0] = (short)f2bf(ok ? v : 0.f);
      }
      f32x4 acc = __builtin_amdgcn_mfma_f32_16x16x32_bf16(Bc1, pf, (f32x4){0.f,0.f,0.f,0.f}, 0, 0, 0);
      int hp = (y+1)*12 + (x+1);
      u16 q0 = f2bf(fmaxf(acc[0] + c1bv[0], 0.f));
      u16 q1 = f2bf(fmaxf(acc[1] + c1bv[1], 0.f));
      u16 q2 = f2bf(fmaxf(acc[2] + c1bv[2], 0.f));
      u16 q3 = f2bf(fmaxf(acc[3] + c1bv[3], 0.f));
      u64 pk = (u64)q0 | ((u64)q1 << 16) | ((u64)q2 << 32) | ((u64)q3 << 48);
      u32 wa = (u32)(((s*108 + hp)*16 + grp*4)*2) ^ (u32)((hp & 7) << 4);
      *(u64*)((char*)act1 + wa) = pk;
    }
    bar_lds();

    for (int mt = w; mt < 35; mt += 8) {
      int row = mt*16 + arow;
      int s = (int)(((u32)row * 59919u) >> 22); int pos = row - s*70;
      int y = (int)(((u32)pos * 6554u) >> 16);  int x = pos - y*10;
      f32x4 acc0 = {0.f,0.f,0.f,0.f}, acc1 = {0.f,0.f,0.f,0.f};
      #pragma unroll
      for (int p = 0; p < 5; p++) {
        int tap = p*2 + (grp >> 1); if (tap > 8) tap = 8;
        int dy = (tap * 11) >> 5; int dx = tap - dy*3;
        int hp = (y + dy)*12 + (x + dx);
        u32 ra = (u32)(((s*108 + hp)*16 + (grp & 1)*8)*2) ^ (u32)((hp & 7) << 4);
        bf16x8 bv = *(const bf16x8*)((const char*)act1 + ra);
        acc0 = __builtin_amdgcn_mfma_f32_16x16x32_bf16(b2f[p][0], bv, acc0, 0, 0, 0);
        acc1 = __builtin_amdgcn_mfma_f32_16x16x32_bf16(b2f[p][1], bv, acc1, 0, 0, 0);
      }
      {
        u16 q0 = f2bf(fmaxf(acc0[0] + c2bv0[0], 0.f));
        u16 q1 = f2bf(fmaxf(acc0[1] + c2bv0[1], 0.f));
        u16 q2 = f2bf(fmaxf(acc0[2] + c2bv0[2], 0.f));
        u16 q3 = f2bf(fmaxf(acc0[3] + c2bv0[3], 0.f));
        u64 pk = (u64)q0 | ((u64)q1 << 16) | ((u64)q2 << 32) | ((u64)q3 << 48);
        *(u64*)(c2g + (size_t)(m0 + s)*2240 + pos*32 + grp*4) = pk;
      }
      {
        u16 q0 = f2bf(fmaxf(acc1[0] + c2bv1[0], 0.f));
        u16 q1 = f2bf(fmaxf(acc1[1] + c2bv1[1], 0.f));
        u16 q2 = f2bf(fmaxf(acc1[2] + c2bv1[2], 0.f));
        u16 q3 = f2bf(fmaxf(acc1[3] + c2bv1[3], 0.f));
        u64 pk = (u64)q0 | ((u64)q1 << 16) | ((u64)q2 << 32) | ((u64)q3 << 48);
        *(u64*)(c2g + (size_t)(m0 + s)*2240 + pos*32 + 16 + grp*4) = pk;
      }
    }
    {
      float a = cfbr;
      #pragma unroll
      for (int k = 0; k < 24; k++) a = fmaf(s_cf[lane][k], s_st[w][70 + k], a);
      ctxg[(size_t)(m0 + w)*64 + lane] = f2bf(fmaxf(a, 0.f));
    }

    if (g < 3) {
      bar_lds();
      if (haspre) *(float2*)&s_st[sst_s][sst_c] = npre;
      bar_lds();
    }
  }
}

// ---------------------------------------------------------------------------
// K1b v4: LDS-staged (coalesced) like v2, but BK=64 (2 K-steps per buffer)
// -> barriers 70 -> 35. Row pad 72 u16 (16B-aligned rows, 2-way bank = free).
// ---------------------------------------------------------------------------
__global__ __launch_bounds__(512, 2) void k_gemm(
    const u16* __restrict__ c2g, const u16* __restrict__ ctxg,
    const float* __restrict__ gfb, const float* __restrict__ tbv,
    const u16* __restrict__ wsb, u16* __restrict__ trunk_ws, int nbase)
{
  __shared__ __align__(16) u16 s_b[2][128*72];   // 36.9 KB
  __shared__ __align__(16) u16 s_g[64*204];      // 26.1 KB

  const int tid  = threadIdx.x;
  const int lane = tid & 63;
  const int w    = tid >> 6;
  const int arow = lane & 15;
  const int grp  = lane >> 4;
  const int wm   = w & 3;
  const int wn   = w >> 2;
  const int m0   = blockIdx.x * 64;

  float gfbv[4], tbvv[4];
  #pragma unroll
  for (int q = 0; q < 4; q++) {
    gfbv[q] = gfb[(wn*4 + q)*16 + arow];
    tbvv[q] = tbv[(wn*4 + q)*16 + arow];
  }

  const int srow = tid >> 2, sseg = (tid & 3) * 16;   // 128 rows x 64 u16
  const u16* wg = wsb + WG_OFF;
  const u16* ap = c2g + (size_t)(m0 + wm*16 + arow) * 2240 + grp*8;

  // prologue: stage pair 0; A pairs (0,1) and (2,3)
  {
    const u16* src = wg + (size_t)srow*2240 + sseg;
    *(uint4*)&s_b[0][srow*72 + sseg]     = *(const uint4*)src;
    *(uint4*)&s_b[0][srow*72 + sseg + 8] = *(const uint4*)(src + 8);
  }
  bf16x8 aC0 = *(const bf16x8*)(ap);
  bf16x8 aC1 = *(const bf16x8*)(ap + 32);
  bf16x8 aN0 = *(const bf16x8*)(ap + 64);
  bf16x8 aN1 = *(const bf16x8*)(ap + 96);
  f32x4 acc[4];
  #pragma unroll
  for (int q = 0; q < 4; q++) acc[q] = (f32x4){0.f,0.f,0.f,0.f};
  __syncthreads();

  for (int kp = 0; kp < 35; kp++) {
    // load next B pair (parked after compute)
    uint4 b0v, b1v;
    if (kp < 34) {
      const u16* src = wg + (size_t)srow*2240 + (kp+1)*64 + sseg;
      b0v = *(const uint4*)src;
      b1v = *(const uint4*)(src + 8);
    }
    // load future A pair
    bf16x8 aF0 = aN0, aF1 = aN1;
    if (kp < 33) {
      aF0 = *(const bf16x8*)(ap + (size_t)(kp+2)*64);
      aF1 = *(const bf16x8*)(ap + (size_t)(kp+2)*64 + 32);
    }
    // compute pair kp
    const u16* sb = &s_b[kp & 1][0];
    #pragma unroll
    for (int q = 0; q < 4; q++) {
      bf16x8 bv0 = *(const bf16x8*)&sb[((wn*4 + q)*16 + arow)*72 + grp*8];
      acc[q] = __builtin_amdgcn_mfma_f32_16x16x32_bf16(aC0, bv0, acc[q], 0, 0, 0);
    }
    #pragma unroll
    for (int q = 0; q < 4; q++) {
      bf16x8 bv1 = *(const bf16x8*)&sb[((wn*4 + q)*16 + arow)*72 + 32 + grp*8];
      acc[q] = __builtin_amdgcn_mfma_f32_16x16x32_bf16(aC1, bv1, acc[q], 0, 0, 0);
    }
    // park next B pair
    if (kp < 34) {
      *(uint4*)&s_b[(kp+1) & 1][srow*72 + sseg]     = b0v;
      *(uint4*)&s_b[(kp+1) & 1][srow*72 + sseg + 8] = b1v;
    }
    aC0 = aN0; aC1 = aN1; aN0 = aF0; aN1 = aF1;
    bar_lds();
  }

  // epilogue (verbatim v2): grid_fc -> s_g + ctx, trunk, store
  #pragma unroll
  for (int q = 0; q < 4; q++)
    #pragma unroll
    for (int r = 0; r < 4; r++)
      s_g[(wm*16 + grp*4 + r)*204 + (wn*4 + q)*16 + arow] = f2bf(fmaxf(acc[q][r] + gfbv[q], 0.f));
  {
    int row = tid >> 3, seg = (tid & 7) * 8;
    uint4 c0 = *(const uint4*)(ctxg + (size_t)(m0 + row)*64 + seg);
    *(uint4*)&s_g[row*204 + 128 + seg] = c0;
  }
  bar_lds();

  f32x4 tacc[4];
  #pragma unroll
  for (int q = 0; q < 4; q++) tacc[q] = (f32x4){0.f,0.f,0.f,0.f};
  #pragma unroll
  for (int ks = 0; ks < 6; ks++) {
    bf16x8 av = *(const bf16x8*)&s_g[(wm*16 + arow)*204 + ks*32 + grp*8];
    #pragma unroll
    for (int q = 0; q < 4; q++) {
      bf16x8 bv = *(const bf16x8*)(wsb + WT_OFF + (size_t)((wn*4 + q)*16 + arow)*192 + ks*32 + grp*8);
      tacc[q] = __builtin_amdgcn_mfma_f32_16x16x32_bf16(av, bv, tacc[q], 0, 0, 0);
    }
  }
  bar_lds();
  #pragma unroll
  for (int q = 0; q < 4; q++)
    #pragma unroll
    for (int r = 0; r < 4; r++)
      s_g[(wm*16 + grp*4 + r)*204 + (wn*4 + q)*16 + arow] = f2bf(fmaxf(tacc[q][r] + tbvv[q], 0.f));
  bar_lds();

  {
    const int t0 = (nbase + m0) & 127;
    const int bb = (nbase + m0) >> 7;
    int row = tid >> 3, seg = (tid & 7) * 16;
    #pragma unroll
    for (int j = 0; j < 2; j++) {
      uint4 v = *(const uint4*)&s_g[row*204 + seg + j*8];
      *(uint4*)(trunk_ws + ((size_t)(t0 + row)*B_ + bb)*128 + seg + j*8) = v;
    }
  }
}

// ---------------------------------------------------------------------------
// K1c: k_xg (verbatim).
// ---------------------------------------------------------------------------
__global__ __launch_bounds__(512, 2) void k_xg(
    const u16* __restrict__ trunk_ws, const u16* __restrict__ wsb,
    u16* __restrict__ gxg)
{
  const int tid  = threadIdx.x;
  const int lane = tid & 63;
  const int w    = tid >> 6;
  const int arow = lane & 15;
  const int grp  = lane >> 4;
  const int t    = blockIdx.x >> 3;
  const int bch  = (blockIdx.x & 7) * 128;
  const int samp = bch + w*16 + arow;

  bf16x8 bv[4];
  #pragma unroll
  for (int ks = 0; ks < 4; ks++)
    bv[ks] = *(const bf16x8*)(trunk_ws + ((size_t)t*B_ + samp)*128 + ks*32 + grp*8);

  const u16* wip = wsb + WIH_OFF;
  u16* gout = gxg + ((size_t)t*B_ + samp)*512;

  #pragma unroll 1
  for (int ntb = 0; ntb < 32; ntb += 4) {
    f32x4 acc[4];
    #pragma unroll
    for (int q = 0; q < 4; q++) acc[q] = (f32x4){0.f,0.f,0.f,0.f};
    #pragma unroll
    for (int ks = 0; ks < 4; ks++) {
      #pragma unroll
      for (int q = 0; q < 4; q++) {
        bf16x8 aw = *(const bf16x8*)(wip + (size_t)((ntb+q)*16 + arow)*128 + ks*32 + grp*8);
        acc[q] = __builtin_amdgcn_mfma_f32_16x16x32_bf16(aw, bv[ks], acc[q], 0, 0, 0);
      }
    }
    #pragma unroll
    for (int q = 0; q < 4; q++) {
      u16 q0 = f2bf(acc[q][0]);
      u16 q1 = f2bf(acc[q][1]);
      u16 q2 = f2bf(acc[q][2]);
      u16 q3 = f2bf(acc[q][3]);
      u64 pk = (u64)q0 | ((u64)q1 << 16) | ((u64)q2 << 32) | ((u64)q3 << 48);
      *(u64*)(gout + (ntb+q)*16 + grp*4) = pk;
    }
  }
}

// ---------------------------------------------------------------------------
// K2: MFMA LSTM v5 (verbatim — at dependency floor).
// ---------------------------------------------------------------------------
__global__ __launch_bounds__(512, 1) void k_lstm(
    const u16* __restrict__ gxg, const float* __restrict__ whh,
    const float* __restrict__ bih, u16* __restrict__ h_ws)
{
  __shared__ __align__(16) u16 s_h[2][16*136];

  const int tid  = threadIdx.x;
  const int lane = tid & 63;
  const int w    = tid >> 6;
  const int arow = lane & 15;
  const int grp  = lane >> 4;
  const int b0   = blockIdx.x * 4;

  bf16x8 Bv[4][4];
  float bihv[4];
  #pragma unroll
  for (int j = 0; j < 4; j++) {
    const int row = j*128 + w*16 + arow;
    bihv[j] = bih[row];
    #pragma unroll
    for (int ks = 0; ks < 4; ks++) {
      const float* s1 = whh + (size_t)row*128 + ks*32 + grp*8;
      float4 a0 = *(const float4*)s1, a1 = *(const float4*)(s1 + 4);
      bf16x8 t1;
      t1[0]=(short)f2bf(a0.x); t1[1]=(short)f2bf(a0.y); t1[2]=(short)f2bf(a0.z); t1[3]=(short)f2bf(a0.w);
      t1[4]=(short)f2bf(a1.x); t1[5]=(short)f2bf(a1.y); t1[6]=(short)f2bf(a1.z); t1[7]=(short)f2bf(a1.w);
      Bv[j][ks] = t1;
    }
  }

  for (int i = tid; i < 2*16*136; i += 512) ((u16*)s_h)[i] = 0;

  const u16* gxb = gxg + ((size_t)(b0 + grp))*512 + w*16 + arow;
  u16 Gc[4], Gn[4];
  #pragma unroll
  for (int j = 0; j < 4; j++) {
    Gc[j] = gxb[(size_t)0*B_*512 + j*128];
    Gn[j] = gxb[(size_t)1*B_*512 + j*128];
  }

  const int prow = tid >> 4, pseg = (tid & 15) * 8;
  float cst = 0.f;
  __syncthreads();

  for (int t = 0; t < T_; t++) {
    const int p = t & 1;

    u16 Gf[4] = {0,0,0,0};
    if (t + 2 < T_) {
      #pragma unroll
      for (int j = 0; j < 4; j++)
        Gf[j] = gxb[(size_t)(t+2)*B_*512 + j*128];
    }
    if (t > 0 && tid < 64) {
      uint4 hv = *(const uint4*)&s_h[p][prow*136 + pseg];
      *(uint4*)(h_ws + ((size_t)(t-1)*B_ + b0 + prow)*128 + pseg) = hv;
    }

    f32x4 racc[4];
    #pragma unroll
    for (int j = 0; j < 4; j++) racc[j] = (f32x4){0.f,0.f,0.f,0.f};
    #pragma unroll
    for (int ks = 0; ks < 4; ks++) {
      bf16x8 av = *(const bf16x8*)&s_h[p][arow*136 + ks*32 + grp*8];
      #pragma unroll
      for (int j = 0; j < 4; j++)
        racc[j] = __builtin_amdgcn_mfma_f32_16x16x32_bf16(av, Bv[j][ks], racc[j], 0, 0, 0);
    }

    float g4[4];
    #pragma unroll
    for (int j = 0; j < 4; j++) {
      float t0v = __shfl(racc[j][0], arow);
      float t1v = __shfl(racc[j][1], arow);
      float t2v = __shfl(racc[j][2], arow);
      float t3v = __shfl(racc[j][3], arow);
      g4[j] = (grp == 0) ? t0v : (grp == 1) ? t1v : (grp == 2) ? t2v : t3v;
    }

    {
      float xi = g4[0] + bf2f(Gc[0]) + bihv[0];
      float xf = g4[1] + bf2f(Gc[1]) + bihv[1];
      float xg = g4[2] + bf2f(Gc[2]) + bihv[2];
      float xo = g4[3] + bf2f(Gc[3]) + bihv[3];
      float I = sigm(xi), F = sigm(xf), O = sigm(xo), G = tanh_f(xg);
      cst = F*cst + I*G;
      float hvv = O * tanh_f(cst);
      s_h[1-p][grp*136 + w*16 + arow] = f2bf(hvv);
    }

    #pragma unroll
    for (int j = 0; j < 4; j++) { Gc[j] = Gn[j]; Gn[j] = Gf[j]; }
    bar_lds();
  }

  if (tid < 64) {
    uint4 hv = *(const uint4*)&s_h[T_ & 1][prow*136 + pseg];
    *(uint4*)(h_ws + ((size_t)(T_-1)*B_ + b0 + prow)*128 + pseg) = hv;
  }
}

// ---------------------------------------------------------------------------
// K3: heads (verbatim).
// ---------------------------------------------------------------------------
__global__ __launch_bounds__(256, 1) void k_heads(
    const u16* __restrict__ h_ws, const int* __restrict__ actions,
    const float* __restrict__ aw, const float* __restrict__ ab,
    const float* __restrict__ cw, const float* __restrict__ cb,
    float* __restrict__ out)
{
  const int tid  = threadIdx.x;
  const int lane = tid & 63;
  const int w    = tid >> 6;
  const int arow = lane & 15;
  const int grp  = lane >> 4;

  bf16x8 Ah[4];
  #pragma unroll
  for (int ks = 0; ks < 4; ks++) {
    bf16x8 v = {0,0,0,0,0,0,0,0};
    if (arow < 4) {
      const float* src = aw + arow*128 + ks*32 + grp*8;
      #pragma unroll
      for (int j = 0; j < 8; j++) v[j] = (short)f2bf(src[j]);
    } else if (arow == 4) {
      const float* src = cw + ks*32 + grp*8;
      #pragma unroll
      for (int j = 0; j < 8; j++) v[j] = (short)f2bf(src[j]);
    }
    Ah[ks] = v;
  }
  const float ab0=ab[0], ab1=ab[1], ab2=ab[2], ab3=ab[3], cb0=cb[0];

  #pragma unroll
  for (int g = 0; g < 4; g++) {
    int m0 = (blockIdx.x*4 + w)*64 + g*16;
    int t  = m0 >> 10; int bb = m0 & 1023;
    f32x4 acc = {0.f,0.f,0.f,0.f};
    #pragma unroll
    for (int ks = 0; ks < 4; ks++) {
      bf16x8 bv = *(const bf16x8*)(h_ws + ((size_t)t*B_ + bb + arow)*128 + ks*32 + grp*8);
      acc = __builtin_amdgcn_mfma_f32_16x16x32_bf16(Ah[ks], bv, acc, 0, 0, 0);
    }
    float cr = __shfl_xor(acc[0], 16);
    if (grp == 0) {
      float L0 = acc[0] + ab0, L1 = acc[1] + ab1, L2 = acc[2] + ab2, L3 = acc[3] + ab3;
      float Lv = cr + cb0;
      float mm = fmaxf(fmaxf(L0, L1), fmaxf(L2, L3));
      float e0 = __expf(L0-mm), e1 = __expf(L1-mm), e2 = __expf(L2-mm), e3 = __expf(L3-mm);
      float S = e0+e1+e2+e3; float lse = __logf(S);
      float p0=L0-mm-lse, p1=L1-mm-lse, p2=L2-mm-lse, p3=L3-mm-lse;
      int n = (bb + arow)*T_ + t;
      int a = actions[n];
      float lpa = (a==0)?p0:(a==1)?p1:(a==2)?p2:p3;
      float ent = -(e0*p0 + e1*p1 + e2*p2 + e3*p3) / S;
      out[n] = lpa; out[NBT + n] = Lv; out[2*NBT + n] = ent;
    }
  }
}

extern "C" void kernel_launch(void* const* d_in, const int* in_sizes, int n_in,
                              void* d_out, int out_size, void* d_ws, size_t ws_size,
                              hipStream_t stream) {
  const float* states = (const float*)d_in[0];
  const int*   actions= (const int*)  d_in[1];
  const float* c1w = (const float*)d_in[2];
  const float* c1b = (const float*)d_in[3];
  const float* c2w = (const float*)d_in[4];
  const float* c2b = (const float*)d_in[5];
  const float* gfw = (const float*)d_in[6];
  const float* gfb = (const float*)d_in[7];
  const float* cfw = (const float*)d_in[8];
  const float* cfb = (const float*)d_in[9];
  const float* tw  = (const float*)d_in[10];
  const float* tbv = (const float*)d_in[11];
  const float* wih = (const float*)d_in[12];
  const float* bih = (const float*)d_in[13];
  const float* whh = (const float*)d_in[14];
  const float* aw  = (const float*)d_in[15];
  const float* ab  = (const float*)d_in[16];
  const float* cw  = (const float*)d_in[17];
  const float* cb  = (const float*)d_in[18];
  float* out = (float*)d_out;

  u16* wsb   = (u16*)d_ws;
  u16* trunk = (u16*)((char*)d_ws + TRUNK_OFF);
  u16* h_ws  = (u16*)((char*)d_ws + H_OFF);
  u16* ctxg  = (u16*)((char*)d_ws + CTX_OFF);
  u16* c2g   = (u16*)((char*)d_ws + C2_OFF);
  u16* gxg   = (u16*)((char*)d_ws + GX_OFF);

  k_cvt<<<(CVT_TOTAL + 255)/256, 256, 0, stream>>>(gfw, tw, wih, c2w, c1w, wsb);

  for (int c = 0; c < NCHUNK; c++) {
    const float* st_c = states + (size_t)c * CHUNK * 94;
    u16* ctx_c = ctxg + (size_t)c * CHUNK * 64;
    k_conv<<<CHUNK/32, 512, 0, stream>>>(st_c, c1b, c2b, cfw, cfb, wsb, c2g, ctx_c);
    k_gemm<<<CHUNK/64, 512, 0, stream>>>(c2g, ctx_c, gfb, tbv, wsb, trunk, c*CHUNK);
  }
  k_xg<<<T_*8, 512, 0, stream>>>(trunk, wsb, gxg);
  k_lstm<<<B_/4, 512, 0, stream>>>(gxg, whh, bih, h_ws);
  k_heads<<<512, 256, 0, stream>>>(h_ws, actions, aw, ab, cw, cb, out);
}

// Round 16
// 791.425 us; speedup vs baseline: 1.5728x; 1.0157x over previous
//
#include <hip/hip_runtime.h>
#include <hip/hip_bf16.h>

typedef unsigned int  u32;
typedef unsigned short u16;
typedef unsigned long long u64;
typedef __attribute__((ext_vector_type(8))) short bf16x8;
typedef __attribute__((ext_vector_type(4))) float f32x4;

#define B_   1024
#define T_   128
#define NBT  (B_*T_)
#define CHUNK 32768
#define NCHUNK 4

// ---- wsb (u16 element offsets) ----
#define WG_OFF   0
#define WT_OFF   286720
#define WIH_OFF  311296
#define W2_OFF   376832
#define W1C_OFF  381952
#define CVT_TOTAL 382464

// ---- d_ws byte offsets ----
#define TRUNK_OFF (1ull<<20)
#define H_OFF     (36ull<<20)
#define CTX_OFF   (72ull<<20)
#define C2_OFF    (92ull<<20)
#define GX_OFF    C2_OFF

__device__ __forceinline__ u16 f2bf(float f){
  __hip_bfloat16 h = __float2bfloat16(f);     // RNE; compiler can pair into v_cvt_pk_bf16_f32
  return *reinterpret_cast<u16*>(&h);
}
__device__ __forceinline__ float bf2f(u16 u){ return __uint_as_float((u32)u << 16); }
__device__ __forceinline__ float sigm(float x){ return 1.f / (1.f + __expf(-x)); }
__device__ __forceinline__ float tanh_f(float x){ return 2.f / (1.f + __expf(-2.f*x)) - 1.f; }

__device__ __forceinline__ void bar_lds() {
  __builtin_amdgcn_sched_barrier(0);
  asm volatile("s_waitcnt lgkmcnt(0)" ::: "memory");
  __builtin_amdgcn_s_barrier();
  __builtin_amdgcn_sched_barrier(0);
}

// ---------------------------------------------------------------------------
// K0 (verbatim)
// ---------------------------------------------------------------------------
__global__ void k_cvt(const float* __restrict__ gfw, const float* __restrict__ tw,
                      const float* __restrict__ wih, const float* __restrict__ c2w,
                      const float* __restrict__ c1w, u16* __restrict__ wsb) {
  int i = blockIdx.x * 256 + threadIdx.x;
  if (i >= CVT_TOTAL) return;
  float v;
  if (i < WT_OFF) {
    int o = i / 2240; int k = i - o*2240;
    int pos = k >> 5, ch = k & 31;
    v = gfw[o*2240 + ch*70 + pos];
  }
  else if (i < WIH_OFF)  v = tw[i - WT_OFF];
  else if (i < W2_OFF)   v = wih[i - WIH_OFF];
  else if (i < W1C_OFF) {
    int j = i - W2_OFF; int co = j / 160; int k = j - co*160;
    int tap = k >> 4; int ci = k & 15;
    v = (tap < 9) ? c2w[co*144 + ci*9 + tap] : 0.f;
  } else {
    int j = i - W1C_OFF; int ch = j >> 5; int k = j & 31;
    v = (k < 9) ? c1w[ch*9 + k] : 0.f;
  }
  wsb[i] = f2bf(v);
}

// ---------------------------------------------------------------------------
// K1a v3: conv1 + conv2 + ctx_fc. 64 samples/block in 8 groups of 8
// (setup amortized 2x vs v2); ctx weights in REGISTERS (no s_cf LDS reads).
// ---------------------------------------------------------------------------
__global__ __launch_bounds__(512, 4) void k_conv(
    const float* __restrict__ states,
    const float* __restrict__ c1b, const float* __restrict__ c2b,
    const float* __restrict__ cfw, const float* __restrict__ cfb,
    const u16* __restrict__ wsb,
    u16* __restrict__ c2g,
    u16* __restrict__ ctxg)
{
  __shared__ float s_st[8][96];
  __shared__ __align__(16) u16 act1[8*108*16];

  const int tid  = threadIdx.x;
  const int lane = tid & 63;
  const int w    = tid >> 6;
  const int arow = lane & 15;
  const int grp  = lane >> 4;
  const int g0   = blockIdx.x * 64;   // 8 groups of 8 samples

  bf16x8 Bc1 = *(const bf16x8*)(wsb + W1C_OFF + arow*32 + grp*8);
  bf16x8 b2f[5][2];
  #pragma unroll
  for (int p = 0; p < 5; p++)
    #pragma unroll
    for (int nt = 0; nt < 2; nt++)
      b2f[p][nt] = *(const bf16x8*)(wsb + W2_OFF + (nt*16 + arow)*160 + p*32 + grp*8);
  float c1bv[4], c2bv0[4], c2bv1[4];
  #pragma unroll
  for (int r = 0; r < 4; r++) {
    c1bv[r]  = c1b[grp*4 + r];
    c2bv0[r] = c2b[grp*4 + r];
    c2bv1[r] = c2b[16 + grp*4 + r];
  }
  // ctx weights in registers (lane = out index)
  const float cfbr = cfb[lane];
  float cfwr[24];
  #pragma unroll
  for (int k = 0; k < 24; k++) cfwr[k] = cfw[lane*24 + k];

  const int sst_s = (tid*2)/94, sst_c = (tid*2)%94;

  if (tid < 376) {
    float2 v = *(const float2*)(states + (size_t)g0*94 + tid*2);
    *(float2*)&s_st[sst_s][sst_c] = v;
  }
  for (int i = tid; i < 608; i += 512) {
    int s = i / 76; int r = i - s*76; int hi2 = r >> 1; int h = r & 1;
    int hp;
    if (hi2 < 12)      hp = hi2;
    else if (hi2 < 24) hp = 96 + (hi2 - 12);
    else if (hi2 < 31) hp = (hi2 - 23) * 12;
    else               hp = (hi2 - 30) * 12 + 11;
    u32 a = (u32)((s*108 + hp)*32 + h*16) ^ (u32)((hp & 7) << 4);
    *(uint4*)((char*)act1 + a) = (uint4){0,0,0,0};
  }
  bar_lds();

  const bf16x8 zv = {0,0,0,0,0,0,0,0};

  for (int g = 0; g < 8; g++) {
    const int m0 = g0 + g*8;
    float2 npre;
    const bool haspre = (g < 7) && (tid < 376);
    if (haspre)
      npre = *(const float2*)(states + (size_t)(m0 + 8)*94 + tid*2);

    // ---- conv1 MFMA ----
    for (int mt = w; mt < 35; mt += 8) {
      int row = mt*16 + arow;
      int s = (int)(((u32)row * 59919u) >> 22); int pos = row - s*70;
      int y = (int)(((u32)pos * 6554u) >> 16);  int x = pos - y*10;
      bf16x8 pf = zv;
      if (grp == 0) {
        const float* gs = &s_st[s][0];
        #pragma unroll
        for (int t = 0; t < 8; t++) {
          int dy = t/3, dx = t - (t/3)*3;
          int yy = y + dy - 1, xx = x + dx - 1;
          bool ok = (yy >= 0) & (yy < 7) & (xx >= 0) & (xx < 10);
          float v = gs[ok ? yy*10 + xx : 0];
          pf[t] = (short)f2bf(ok ? v : 0.f);
        }
      } else if (grp == 1) {
        int yy = y + 1, xx = x + 1;
        bool ok = (yy < 7) & (xx < 10);
        float v = s_st[s][ok ? yy*10 + xx : 0];
        pf[0] = (short)f2bf(ok ? v : 0.f);
      }
      f32x4 acc = __builtin_amdgcn_mfma_f32_16x16x32_bf16(Bc1, pf, (f32x4){0.f,0.f,0.f,0.f}, 0, 0, 0);
      int hp = (y+1)*12 + (x+1);
      u16 q0 = f2bf(fmaxf(acc[0] + c1bv[0], 0.f));
      u16 q1 = f2bf(fmaxf(acc[1] + c1bv[1], 0.f));
      u16 q2 = f2bf(fmaxf(acc[2] + c1bv[2], 0.f));
      u16 q3 = f2bf(fmaxf(acc[3] + c1bv[3], 0.f));
      u64 pk = (u64)q0 | ((u64)q1 << 16) | ((u64)q2 << 32) | ((u64)q3 << 48);
      u32 wa = (u32)(((s*108 + hp)*16 + grp*4)*2) ^ (u32)((hp & 7) << 4);
      *(u64*)((char*)act1 + wa) = pk;
    }
    bar_lds();

    // ---- conv2 MFMA + ctx ----
    for (int mt = w; mt < 35; mt += 8) {
      int row = mt*16 + arow;
      int s = (int)(((u32)row * 59919u) >> 22); int pos = row - s*70;
      int y = (int)(((u32)pos * 6554u) >> 16);  int x = pos - y*10;
      f32x4 acc0 = {0.f,0.f,0.f,0.f}, acc1 = {0.f,0.f,0.f,0.f};
      #pragma unroll
      for (int p = 0; p < 5; p++) {
        int tap = p*2 + (grp >> 1); if (tap > 8) tap = 8;
        int dy = (tap * 11) >> 5; int dx = tap - dy*3;
        int hp = (y + dy)*12 + (x + dx);
        u32 ra = (u32)(((s*108 + hp)*16 + (grp & 1)*8)*2) ^ (u32)((hp & 7) << 4);
        bf16x8 bv = *(const bf16x8*)((const char*)act1 + ra);
        acc0 = __builtin_amdgcn_mfma_f32_16x16x32_bf16(b2f[p][0], bv, acc0, 0, 0, 0);
        acc1 = __builtin_amdgcn_mfma_f32_16x16x32_bf16(b2f[p][1], bv, acc1, 0, 0, 0);
      }
      {
        u16 q0 = f2bf(fmaxf(acc0[0] + c2bv0[0], 0.f));
        u16 q1 = f2bf(fmaxf(acc0[1] + c2bv0[1], 0.f));
        u16 q2 = f2bf(fmaxf(acc0[2] + c2bv0[2], 0.f));
        u16 q3 = f2bf(fmaxf(acc0[3] + c2bv0[3], 0.f));
        u64 pk = (u64)q0 | ((u64)q1 << 16) | ((u64)q2 << 32) | ((u64)q3 << 48);
        *(u64*)(c2g + (size_t)(m0 + s)*2240 + pos*32 + grp*4) = pk;
      }
      {
        u16 q0 = f2bf(fmaxf(acc1[0] + c2bv1[0], 0.f));
        u16 q1 = f2bf(fmaxf(acc1[1] + c2bv1[1], 0.f));
        u16 q2 = f2bf(fmaxf(acc1[2] + c2bv1[2], 0.f));
        u16 q3 = f2bf(fmaxf(acc1[3] + c2bv1[3], 0.f));
        u64 pk = (u64)q0 | ((u64)q1 << 16) | ((u64)q2 << 32) | ((u64)q3 << 48);
        *(u64*)(c2g + (size_t)(m0 + s)*2240 + pos*32 + 16 + grp*4) = pk;
      }
    }
    {
      float a = cfbr;
      #pragma unroll
      for (int k = 0; k < 24; k++) a = fmaf(cfwr[k], s_st[w][70 + k], a);
      ctxg[(size_t)(m0 + w)*64 + lane] = f2bf(fmaxf(a, 0.f));
    }

    if (g < 7) {
      bar_lds();
      if (haspre) *(float2*)&s_st[sst_s][sst_c] = npre;
      bar_lds();
    }
  }
}

// ---------------------------------------------------------------------------
// K1b v4 (verbatim R15 — WON, keep): BK=64 LDS-staged GEMM.
// ---------------------------------------------------------------------------
__global__ __launch_bounds__(512, 2) void k_gemm(
    const u16* __restrict__ c2g, const u16* __restrict__ ctxg,
    const float* __restrict__ gfb, const float* __restrict__ tbv,
    const u16* __restrict__ wsb, u16* __restrict__ trunk_ws, int nbase)
{
  __shared__ __align__(16) u16 s_b[2][128*72];
  __shared__ __align__(16) u16 s_g[64*204];

  const int tid  = threadIdx.x;
  const int lane = tid & 63;
  const int w    = tid >> 6;
  const int arow = lane & 15;
  const int grp  = lane >> 4;
  const int wm   = w & 3;
  const int wn   = w >> 2;
  const int m0   = blockIdx.x * 64;

  float gfbv[4], tbvv[4];
  #pragma unroll
  for (int q = 0; q < 4; q++) {
    gfbv[q] = gfb[(wn*4 + q)*16 + arow];
    tbvv[q] = tbv[(wn*4 + q)*16 + arow];
  }

  const int srow = tid >> 2, sseg = (tid & 3) * 16;
  const u16* wg = wsb + WG_OFF;
  const u16* ap = c2g + (size_t)(m0 + wm*16 + arow) * 2240 + grp*8;

  {
    const u16* src = wg + (size_t)srow*2240 + sseg;
    *(uint4*)&s_b[0][srow*72 + sseg]     = *(const uint4*)src;
    *(uint4*)&s_b[0][srow*72 + sseg + 8] = *(const uint4*)(src + 8);
  }
  bf16x8 aC0 = *(const bf16x8*)(ap);
  bf16x8 aC1 = *(const bf16x8*)(ap + 32);
  bf16x8 aN0 = *(const bf16x8*)(ap + 64);
  bf16x8 aN1 = *(const bf16x8*)(ap + 96);
  f32x4 acc[4];
  #pragma unroll
  for (int q = 0; q < 4; q++) acc[q] = (f32x4){0.f,0.f,0.f,0.f};
  __syncthreads();

  for (int kp = 0; kp < 35; kp++) {
    uint4 b0v, b1v;
    if (kp < 34) {
      const u16* src = wg + (size_t)srow*2240 + (kp+1)*64 + sseg;
      b0v = *(const uint4*)src;
      b1v = *(const uint4*)(src + 8);
    }
    bf16x8 aF0 = aN0, aF1 = aN1;
    if (kp < 33) {
      aF0 = *(const bf16x8*)(ap + (size_t)(kp+2)*64);
      aF1 = *(const bf16x8*)(ap + (size_t)(kp+2)*64 + 32);
    }
    const u16* sb = &s_b[kp & 1][0];
    #pragma unroll
    for (int q = 0; q < 4; q++) {
      bf16x8 bv0 = *(const bf16x8*)&sb[((wn*4 + q)*16 + arow)*72 + grp*8];
      acc[q] = __builtin_amdgcn_mfma_f32_16x16x32_bf16(aC0, bv0, acc[q], 0, 0, 0);
    }
    #pragma unroll
    for (int q = 0; q < 4; q++) {
      bf16x8 bv1 = *(const bf16x8*)&sb[((wn*4 + q)*16 + arow)*72 + 32 + grp*8];
      acc[q] = __builtin_amdgcn_mfma_f32_16x16x32_bf16(aC1, bv1, acc[q], 0, 0, 0);
    }
    if (kp < 34) {
      *(uint4*)&s_b[(kp+1) & 1][srow*72 + sseg]     = b0v;
      *(uint4*)&s_b[(kp+1) & 1][srow*72 + sseg + 8] = b1v;
    }
    aC0 = aN0; aC1 = aN1; aN0 = aF0; aN1 = aF1;
    bar_lds();
  }

  #pragma unroll
  for (int q = 0; q < 4; q++)
    #pragma unroll
    for (int r = 0; r < 4; r++)
      s_g[(wm*16 + grp*4 + r)*204 + (wn*4 + q)*16 + arow] = f2bf(fmaxf(acc[q][r] + gfbv[q], 0.f));
  {
    int row = tid >> 3, seg = (tid & 7) * 8;
    uint4 c0 = *(const uint4*)(ctxg + (size_t)(m0 + row)*64 + seg);
    *(uint4*)&s_g[row*204 + 128 + seg] = c0;
  }
  bar_lds();

  f32x4 tacc[4];
  #pragma unroll
  for (int q = 0; q < 4; q++) tacc[q] = (f32x4){0.f,0.f,0.f,0.f};
  #pragma unroll
  for (int ks = 0; ks < 6; ks++) {
    bf16x8 av = *(const bf16x8*)&s_g[(wm*16 + arow)*204 + ks*32 + grp*8];
    #pragma unroll
    for (int q = 0; q < 4; q++) {
      bf16x8 bv = *(const bf16x8*)(wsb + WT_OFF + (size_t)((wn*4 + q)*16 + arow)*192 + ks*32 + grp*8);
      tacc[q] = __builtin_amdgcn_mfma_f32_16x16x32_bf16(av, bv, tacc[q], 0, 0, 0);
    }
  }
  bar_lds();
  #pragma unroll
  for (int q = 0; q < 4; q++)
    #pragma unroll
    for (int r = 0; r < 4; r++)
      s_g[(wm*16 + grp*4 + r)*204 + (wn*4 + q)*16 + arow] = f2bf(fmaxf(tacc[q][r] + tbvv[q], 0.f));
  bar_lds();

  {
    const int t0 = (nbase + m0) & 127;
    const int bb = (nbase + m0) >> 7;
    int row = tid >> 3, seg = (tid & 7) * 16;
    #pragma unroll
    for (int j = 0; j < 2; j++) {
      uint4 v = *(const uint4*)&s_g[row*204 + seg + j*8];
      *(uint4*)(trunk_ws + ((size_t)(t0 + row)*B_ + bb)*128 + seg + j*8) = v;
    }
  }
}

// ---------------------------------------------------------------------------
// K1c: k_xg (verbatim).
// ---------------------------------------------------------------------------
__global__ __launch_bounds__(512, 2) void k_xg(
    const u16* __restrict__ trunk_ws, const u16* __restrict__ wsb,
    u16* __restrict__ gxg)
{
  const int tid  = threadIdx.x;
  const int lane = tid & 63;
  const int w    = tid >> 6;
  const int arow = lane & 15;
  const int grp  = lane >> 4;
  const int t    = blockIdx.x >> 3;
  const int bch  = (blockIdx.x & 7) * 128;
  const int samp = bch + w*16 + arow;

  bf16x8 bv[4];
  #pragma unroll
  for (int ks = 0; ks < 4; ks++)
    bv[ks] = *(const bf16x8*)(trunk_ws + ((size_t)t*B_ + samp)*128 + ks*32 + grp*8);

  const u16* wip = wsb + WIH_OFF;
  u16* gout = gxg + ((size_t)t*B_ + samp)*512;

  #pragma unroll 1
  for (int ntb = 0; ntb < 32; ntb += 4) {
    f32x4 acc[4];
    #pragma unroll
    for (int q = 0; q < 4; q++) acc[q] = (f32x4){0.f,0.f,0.f,0.f};
    #pragma unroll
    for (int ks = 0; ks < 4; ks++) {
      #pragma unroll
      for (int q = 0; q < 4; q++) {
        bf16x8 aw = *(const bf16x8*)(wip + (size_t)((ntb+q)*16 + arow)*128 + ks*32 + grp*8);
        acc[q] = __builtin_amdgcn_mfma_f32_16x16x32_bf16(aw, bv[ks], acc[q], 0, 0, 0);
      }
    }
    #pragma unroll
    for (int q = 0; q < 4; q++) {
      u16 q0 = f2bf(acc[q][0]);
      u16 q1 = f2bf(acc[q][1]);
      u16 q2 = f2bf(acc[q][2]);
      u16 q3 = f2bf(acc[q][3]);
      u64 pk = (u64)q0 | ((u64)q1 << 16) | ((u64)q2 << 32) | ((u64)q3 << 48);
      *(u64*)(gout + (ntb+q)*16 + grp*4) = pk;
    }
  }
}

// ---------------------------------------------------------------------------
// K2: MFMA LSTM v5 (verbatim — dependency floor).
// ---------------------------------------------------------------------------
__global__ __launch_bounds__(512, 1) void k_lstm(
    const u16* __restrict__ gxg, const float* __restrict__ whh,
    const float* __restrict__ bih, u16* __restrict__ h_ws)
{
  __shared__ __align__(16) u16 s_h[2][16*136];

  const int tid  = threadIdx.x;
  const int lane = tid & 63;
  const int w    = tid >> 6;
  const int arow = lane & 15;
  const int grp  = lane >> 4;
  const int b0   = blockIdx.x * 4;

  bf16x8 Bv[4][4];
  float bihv[4];
  #pragma unroll
  for (int j = 0; j < 4; j++) {
    const int row = j*128 + w*16 + arow;
    bihv[j] = bih[row];
    #pragma unroll
    for (int ks = 0; ks < 4; ks++) {
      const float* s1 = whh + (size_t)row*128 + ks*32 + grp*8;
      float4 a0 = *(const float4*)s1, a1 = *(const float4*)(s1 + 4);
      bf16x8 t1;
      t1[0]=(short)f2bf(a0.x); t1[1]=(short)f2bf(a0.y); t1[2]=(short)f2bf(a0.z); t1[3]=(short)f2bf(a0.w);
      t1[4]=(short)f2bf(a1.x); t1[5]=(short)f2bf(a1.y); t1[6]=(short)f2bf(a1.z); t1[7]=(short)f2bf(a1.w);
      Bv[j][ks] = t1;
    }
  }

  for (int i = tid; i < 2*16*136; i += 512) ((u16*)s_h)[i] = 0;

  const u16* gxb = gxg + ((size_t)(b0 + grp))*512 + w*16 + arow;
  u16 Gc[4], Gn[4];
  #pragma unroll
  for (int j = 0; j < 4; j++) {
    Gc[j] = gxb[(size_t)0*B_*512 + j*128];
    Gn[j] = gxb[(size_t)1*B_*512 + j*128];
  }

  const int prow = tid >> 4, pseg = (tid & 15) * 8;
  float cst = 0.f;
  __syncthreads();

  for (int t = 0; t < T_; t++) {
    const int p = t & 1;

    u16 Gf[4] = {0,0,0,0};
    if (t + 2 < T_) {
      #pragma unroll
      for (int j = 0; j < 4; j++)
        Gf[j] = gxb[(size_t)(t+2)*B_*512 + j*128];
    }
    if (t > 0 && tid < 64) {
      uint4 hv = *(const uint4*)&s_h[p][prow*136 + pseg];
      *(uint4*)(h_ws + ((size_t)(t-1)*B_ + b0 + prow)*128 + pseg) = hv;
    }

    f32x4 racc[4];
    #pragma unroll
    for (int j = 0; j < 4; j++) racc[j] = (f32x4){0.f,0.f,0.f,0.f};
    #pragma unroll
    for (int ks = 0; ks < 4; ks++) {
      bf16x8 av = *(const bf16x8*)&s_h[p][arow*136 + ks*32 + grp*8];
      #pragma unroll
      for (int j = 0; j < 4; j++)
        racc[j] = __builtin_amdgcn_mfma_f32_16x16x32_bf16(av, Bv[j][ks], racc[j], 0, 0, 0);
    }

    float g4[4];
    #pragma unroll
    for (int j = 0; j < 4; j++) {
      float t0v = __shfl(racc[j][0], arow);
      float t1v = __shfl(racc[j][1], arow);
      float t2v = __shfl(racc[j][2], arow);
      float t3v = __shfl(racc[j][3], arow);
      g4[j] = (grp == 0) ? t0v : (grp == 1) ? t1v : (grp == 2) ? t2v : t3v;
    }

    {
      float xi = g4[0] + bf2f(Gc[0]) + bihv[0];
      float xf = g4[1] + bf2f(Gc[1]) + bihv[1];
      float xg = g4[2] + bf2f(Gc[2]) + bihv[2];
      float xo = g4[3] + bf2f(Gc[3]) + bihv[3];
      float I = sigm(xi), F = sigm(xf), O = sigm(xo), G = tanh_f(xg);
      cst = F*cst + I*G;
      float hvv = O * tanh_f(cst);
      s_h[1-p][grp*136 + w*16 + arow] = f2bf(hvv);
    }

    #pragma unroll
    for (int j = 0; j < 4; j++) { Gc[j] = Gn[j]; Gn[j] = Gf[j]; }
    bar_lds();
  }

  if (tid < 64) {
    uint4 hv = *(const uint4*)&s_h[T_ & 1][prow*136 + pseg];
    *(uint4*)(h_ws + ((size_t)(T_-1)*B_ + b0 + prow)*128 + pseg) = hv;
  }
}

// ---------------------------------------------------------------------------
// K3: heads (verbatim).
// ---------------------------------------------------------------------------
__global__ __launch_bounds__(256, 1) void k_heads(
    const u16* __restrict__ h_ws, const int* __restrict__ actions,
    const float* __restrict__ aw, const float* __restrict__ ab,
    const float* __restrict__ cw, const float* __restrict__ cb,
    float* __restrict__ out)
{
  const int tid  = threadIdx.x;
  const int lane = tid & 63;
  const int w    = tid >> 6;
  const int arow = lane & 15;
  const int grp  = lane >> 4;

  bf16x8 Ah[4];
  #pragma unroll
  for (int ks = 0; ks < 4; ks++) {
    bf16x8 v = {0,0,0,0,0,0,0,0};
    if (arow < 4) {
      const float* src = aw + arow*128 + ks*32 + grp*8;
      #pragma unroll
      for (int j = 0; j < 8; j++) v[j] = (short)f2bf(src[j]);
    } else if (arow == 4) {
      const float* src = cw + ks*32 + grp*8;
      #pragma unroll
      for (int j = 0; j < 8; j++) v[j] = (short)f2bf(src[j]);
    }
    Ah[ks] = v;
  }
  const float ab0=ab[0], ab1=ab[1], ab2=ab[2], ab3=ab[3], cb0=cb[0];

  #pragma unroll
  for (int g = 0; g < 4; g++) {
    int m0 = (blockIdx.x*4 + w)*64 + g*16;
    int t  = m0 >> 10; int bb = m0 & 1023;
    f32x4 acc = {0.f,0.f,0.f,0.f};
    #pragma unroll
    for (int ks = 0; ks < 4; ks++) {
      bf16x8 bv = *(const bf16x8*)(h_ws + ((size_t)t*B_ + bb + arow)*128 + ks*32 + grp*8);
      acc = __builtin_amdgcn_mfma_f32_16x16x32_bf16(Ah[ks], bv, acc, 0, 0, 0);
    }
    float cr = __shfl_xor(acc[0], 16);
    if (grp == 0) {
      float L0 = acc[0] + ab0, L1 = acc[1] + ab1, L2 = acc[2] + ab2, L3 = acc[3] + ab3;
      float Lv = cr + cb0;
      float mm = fmaxf(fmaxf(L0, L1), fmaxf(L2, L3));
      float e0 = __expf(L0-mm), e1 = __expf(L1-mm), e2 = __expf(L2-mm), e3 = __expf(L3-mm);
      float S = e0+e1+e2+e3; float lse = __logf(S);
      float p0=L0-mm-lse, p1=L1-mm-lse, p2=L2-mm-lse, p3=L3-mm-lse;
      int n = (bb + arow)*T_ + t;
      int a = actions[n];
      float lpa = (a==0)?p0:(a==1)?p1:(a==2)?p2:p3;
      float ent = -(e0*p0 + e1*p1 + e2*p2 + e3*p3) / S;
      out[n] = lpa; out[NBT + n] = Lv; out[2*NBT + n] = ent;
    }
  }
}

extern "C" void kernel_launch(void* const* d_in, const int* in_sizes, int n_in,
                              void* d_out, int out_size, void* d_ws, size_t ws_size,
                              hipStream_t stream) {
  const float* states = (const float*)d_in[0];
  const int*   actions= (const int*)  d_in[1];
  const float* c1w = (const float*)d_in[2];
  const float* c1b = (const float*)d_in[3];
  const float* c2w = (const float*)d_in[4];
  const float* c2b = (const float*)d_in[5];
  const float* gfw = (const float*)d_in[6];
  const float* gfb = (const float*)d_in[7];
  const float* cfw = (const float*)d_in[8];
  const float* cfb = (const float*)d_in[9];
  const float* tw  = (const float*)d_in[10];
  const float* tbv = (const float*)d_in[11];
  const float* wih = (const float*)d_in[12];
  const float* bih = (const float*)d_in[13];
  const float* whh = (const float*)d_in[14];
  const float* aw  = (const float*)d_in[15];
  const float* ab  = (const float*)d_in[16];
  const float* cw  = (const float*)d_in[17];
  const float* cb  = (const float*)d_in[18];
  float* out = (float*)d_out;

  u16* wsb   = (u16*)d_ws;
  u16* trunk = (u16*)((char*)d_ws + TRUNK_OFF);
  u16* h_ws  = (u16*)((char*)d_ws + H_OFF);
  u16* ctxg  = (u16*)((char*)d_ws + CTX_OFF);
  u16* c2g   = (u16*)((char*)d_ws + C2_OFF);
  u16* gxg   = (u16*)((char*)d_ws + GX_OFF);

  k_cvt<<<(CVT_TOTAL + 255)/256, 256, 0, stream>>>(gfw, tw, wih, c2w, c1w, wsb);

  for (int c = 0; c < NCHUNK; c++) {
    const float* st_c = states + (size_t)c * CHUNK * 94;
    u16* ctx_c = ctxg + (size_t)c * CHUNK * 64;
    k_conv<<<CHUNK/64, 512, 0, stream>>>(st_c, c1b, c2b, cfw, cfb, wsb, c2g, ctx_c);
    k_gemm<<<CHUNK/64, 512, 0, stream>>>(c2g, ctx_c, gfb, tbv, wsb, trunk, c*CHUNK);
  }
  k_xg<<<T_*8, 512, 0, stream>>>(trunk, wsb, gxg);
  k_lstm<<<B_/4, 512, 0, stream>>>(gxg, whh, bih, h_ws);
  k_heads<<<512, 256, 0, stream>>>(h_ws, actions, aw, ab, cw, cb, out);
}

// Round 17
// 689.478 us; speedup vs baseline: 1.8054x; 1.1479x over previous
//
#include <hip/hip_runtime.h>
#include <hip/hip_bf16.h>

typedef unsigned int  u32;
typedef unsigned short u16;
typedef unsigned long long u64;
typedef __attribute__((ext_vector_type(8))) short bf16x8;
typedef __attribute__((ext_vector_type(4))) float f32x4;

#define B_   1024
#define T_   128
#define NBT  (B_*T_)
#define CHUNK 32768
#define NCHUNK 4

// ---- wsb (u16 element offsets) ----
#define WG_OFF   0
#define WT_OFF   286720
#define WIH_OFF  311296
#define W2_OFF   376832
#define W1C_OFF  381952
#define CVT_TOTAL 382464

// ---- d_ws byte offsets ----
#define TRUNK_OFF (1ull<<20)
#define H_OFF     (36ull<<20)
#define CTX_OFF   (72ull<<20)
#define C2_OFF    (92ull<<20)

__device__ __forceinline__ u16 f2bf(float f){
  __hip_bfloat16 h = __float2bfloat16(f);
  return *reinterpret_cast<u16*>(&h);
}
__device__ __forceinline__ float bf2f(u16 u){ return __uint_as_float((u32)u << 16); }
__device__ __forceinline__ float sigm(float x){ return 1.f / (1.f + __expf(-x)); }
__device__ __forceinline__ float tanh_f(float x){ return 2.f / (1.f + __expf(-2.f*x)) - 1.f; }

__device__ __forceinline__ void bar_lds() {
  __builtin_amdgcn_sched_barrier(0);
  asm volatile("s_waitcnt lgkmcnt(0)" ::: "memory");
  __builtin_amdgcn_s_barrier();
  __builtin_amdgcn_sched_barrier(0);
}

// ---------------------------------------------------------------------------
// K0 (verbatim)
// ---------------------------------------------------------------------------
__global__ void k_cvt(const float* __restrict__ gfw, const float* __restrict__ tw,
                      const float* __restrict__ wih, const float* __restrict__ c2w,
                      const float* __restrict__ c1w, u16* __restrict__ wsb) {
  int i = blockIdx.x * 256 + threadIdx.x;
  if (i >= CVT_TOTAL) return;
  float v;
  if (i < WT_OFF) {
    int o = i / 2240; int k = i - o*2240;
    int pos = k >> 5, ch = k & 31;
    v = gfw[o*2240 + ch*70 + pos];
  }
  else if (i < WIH_OFF)  v = tw[i - WT_OFF];
  else if (i < W2_OFF)   v = wih[i - WIH_OFF];
  else if (i < W1C_OFF) {
    int j = i - W2_OFF; int co = j / 160; int k = j - co*160;
    int tap = k >> 4; int ci = k & 15;
    v = (tap < 9) ? c2w[co*144 + ci*9 + tap] : 0.f;
  } else {
    int j = i - W1C_OFF; int ch = j >> 5; int k = j & 31;
    v = (k < 9) ? c1w[ch*9 + k] : 0.f;
  }
  wsb[i] = f2bf(v);
}

// ---------------------------------------------------------------------------
// K1a v3: conv (verbatim R16).
// ---------------------------------------------------------------------------
__global__ __launch_bounds__(512, 4) void k_conv(
    const float* __restrict__ states,
    const float* __restrict__ c1b, const float* __restrict__ c2b,
    const float* __restrict__ cfw, const float* __restrict__ cfb,
    const u16* __restrict__ wsb,
    u16* __restrict__ c2g,
    u16* __restrict__ ctxg)
{
  __shared__ float s_st[8][96];
  __shared__ __align__(16) u16 act1[8*108*16];

  const int tid  = threadIdx.x;
  const int lane = tid & 63;
  const int w    = tid >> 6;
  const int arow = lane & 15;
  const int grp  = lane >> 4;
  const int g0   = blockIdx.x * 64;

  bf16x8 Bc1 = *(const bf16x8*)(wsb + W1C_OFF + arow*32 + grp*8);
  bf16x8 b2f[5][2];
  #pragma unroll
  for (int p = 0; p < 5; p++)
    #pragma unroll
    for (int nt = 0; nt < 2; nt++)
      b2f[p][nt] = *(const bf16x8*)(wsb + W2_OFF + (nt*16 + arow)*160 + p*32 + grp*8);
  float c1bv[4], c2bv0[4], c2bv1[4];
  #pragma unroll
  for (int r = 0; r < 4; r++) {
    c1bv[r]  = c1b[grp*4 + r];
    c2bv0[r] = c2b[grp*4 + r];
    c2bv1[r] = c2b[16 + grp*4 + r];
  }
  const float cfbr = cfb[lane];
  float cfwr[24];
  #pragma unroll
  for (int k = 0; k < 24; k++) cfwr[k] = cfw[lane*24 + k];

  const int sst_s = (tid*2)/94, sst_c = (tid*2)%94;

  if (tid < 376) {
    float2 v = *(const float2*)(states + (size_t)g0*94 + tid*2);
    *(float2*)&s_st[sst_s][sst_c] = v;
  }
  for (int i = tid; i < 608; i += 512) {
    int s = i / 76; int r = i - s*76; int hi2 = r >> 1; int h = r & 1;
    int hp;
    if (hi2 < 12)      hp = hi2;
    else if (hi2 < 24) hp = 96 + (hi2 - 12);
    else if (hi2 < 31) hp = (hi2 - 23) * 12;
    else               hp = (hi2 - 30) * 12 + 11;
    u32 a = (u32)((s*108 + hp)*32 + h*16) ^ (u32)((hp & 7) << 4);
    *(uint4*)((char*)act1 + a) = (uint4){0,0,0,0};
  }
  bar_lds();

  const bf16x8 zv = {0,0,0,0,0,0,0,0};

  for (int g = 0; g < 8; g++) {
    const int m0 = g0 + g*8;
    float2 npre;
    const bool haspre = (g < 7) && (tid < 376);
    if (haspre)
      npre = *(const float2*)(states + (size_t)(m0 + 8)*94 + tid*2);

    for (int mt = w; mt < 35; mt += 8) {
      int row = mt*16 + arow;
      int s = (int)(((u32)row * 59919u) >> 22); int pos = row - s*70;
      int y = (int)(((u32)pos * 6554u) >> 16);  int x = pos - y*10;
      bf16x8 pf = zv;
      if (grp == 0) {
        const float* gs = &s_st[s][0];
        #pragma unroll
        for (int t = 0; t < 8; t++) {
          int dy = t/3, dx = t - (t/3)*3;
          int yy = y + dy - 1, xx = x + dx - 1;
          bool ok = (yy >= 0) & (yy < 7) & (xx >= 0) & (xx < 10);
          float v = gs[ok ? yy*10 + xx : 0];
          pf[t] = (short)f2bf(ok ? v : 0.f);
        }
      } else if (grp == 1) {
        int yy = y + 1, xx = x + 1;
        bool ok = (yy < 7) & (xx < 10);
        float v = s_st[s][ok ? yy*10 + xx : 0];
        pf[0] = (short)f2bf(ok ? v : 0.f);
      }
      f32x4 acc = __builtin_amdgcn_mfma_f32_16x16x32_bf16(Bc1, pf, (f32x4){0.f,0.f,0.f,0.f}, 0, 0, 0);
      int hp = (y+1)*12 + (x+1);
      u16 q0 = f2bf(fmaxf(acc[0] + c1bv[0], 0.f));
      u16 q1 = f2bf(fmaxf(acc[1] + c1bv[1], 0.f));
      u16 q2 = f2bf(fmaxf(acc[2] + c1bv[2], 0.f));
      u16 q3 = f2bf(fmaxf(acc[3] + c1bv[3], 0.f));
      u64 pk = (u64)q0 | ((u64)q1 << 16) | ((u64)q2 << 32) | ((u64)q3 << 48);
      u32 wa = (u32)(((s*108 + hp)*16 + grp*4)*2) ^ (u32)((hp & 7) << 4);
      *(u64*)((char*)act1 + wa) = pk;
    }
    bar_lds();

    for (int mt = w; mt < 35; mt += 8) {
      int row = mt*16 + arow;
      int s = (int)(((u32)row * 59919u) >> 22); int pos = row - s*70;
      int y = (int)(((u32)pos * 6554u) >> 16);  int x = pos - y*10;
      f32x4 acc0 = {0.f,0.f,0.f,0.f}, acc1 = {0.f,0.f,0.f,0.f};
      #pragma unroll
      for (int p = 0; p < 5; p++) {
        int tap = p*2 + (grp >> 1); if (tap > 8) tap = 8;
        int dy = (tap * 11) >> 5; int dx = tap - dy*3;
        int hp = (y + dy)*12 + (x + dx);
        u32 ra = (u32)(((s*108 + hp)*16 + (grp & 1)*8)*2) ^ (u32)((hp & 7) << 4);
        bf16x8 bv = *(const bf16x8*)((const char*)act1 + ra);
        acc0 = __builtin_amdgcn_mfma_f32_16x16x32_bf16(b2f[p][0], bv, acc0, 0, 0, 0);
        acc1 = __builtin_amdgcn_mfma_f32_16x16x32_bf16(b2f[p][1], bv, acc1, 0, 0, 0);
      }
      {
        u16 q0 = f2bf(fmaxf(acc0[0] + c2bv0[0], 0.f));
        u16 q1 = f2bf(fmaxf(acc0[1] + c2bv0[1], 0.f));
        u16 q2 = f2bf(fmaxf(acc0[2] + c2bv0[2], 0.f));
        u16 q3 = f2bf(fmaxf(acc0[3] + c2bv0[3], 0.f));
        u64 pk = (u64)q0 | ((u64)q1 << 16) | ((u64)q2 << 32) | ((u64)q3 << 48);
        *(u64*)(c2g + (size_t)(m0 + s)*2240 + pos*32 + grp*4) = pk;
      }
      {
        u16 q0 = f2bf(fmaxf(acc1[0] + c2bv1[0], 0.f));
        u16 q1 = f2bf(fmaxf(acc1[1] + c2bv1[1], 0.f));
        u16 q2 = f2bf(fmaxf(acc1[2] + c2bv1[2], 0.f));
        u16 q3 = f2bf(fmaxf(acc1[3] + c2bv1[3], 0.f));
        u64 pk = (u64)q0 | ((u64)q1 << 16) | ((u64)q2 << 32) | ((u64)q3 << 48);
        *(u64*)(c2g + (size_t)(m0 + s)*2240 + pos*32 + 16 + grp*4) = pk;
      }
    }
    {
      float a = cfbr;
      #pragma unroll
      for (int k = 0; k < 24; k++) a = fmaf(cfwr[k], s_st[w][70 + k], a);
      ctxg[(size_t)(m0 + w)*64 + lane] = f2bf(fmaxf(a, 0.f));
    }

    if (g < 7) {
      bar_lds();
      if (haspre) *(float2*)&s_st[sst_s][sst_c] = npre;
      bar_lds();
    }
  }
}

// ---------------------------------------------------------------------------
// K1b v4 (verbatim R16): BK=64 LDS-staged GEMM; stores trunk (k_lstm input).
// ---------------------------------------------------------------------------
__global__ __launch_bounds__(512, 2) void k_gemm(
    const u16* __restrict__ c2g, const u16* __restrict__ ctxg,
    const float* __restrict__ gfb, const float* __restrict__ tbv,
    const u16* __restrict__ wsb, u16* __restrict__ trunk_ws, int nbase)
{
  __shared__ __align__(16) u16 s_b[2][128*72];
  __shared__ __align__(16) u16 s_g[64*204];

  const int tid  = threadIdx.x;
  const int lane = tid & 63;
  const int w    = tid >> 6;
  const int arow = lane & 15;
  const int grp  = lane >> 4;
  const int wm   = w & 3;
  const int wn   = w >> 2;
  const int m0   = blockIdx.x * 64;

  float gfbv[4], tbvv[4];
  #pragma unroll
  for (int q = 0; q < 4; q++) {
    gfbv[q] = gfb[(wn*4 + q)*16 + arow];
    tbvv[q] = tbv[(wn*4 + q)*16 + arow];
  }

  const int srow = tid >> 2, sseg = (tid & 3) * 16;
  const u16* wg = wsb + WG_OFF;
  const u16* ap = c2g + (size_t)(m0 + wm*16 + arow) * 2240 + grp*8;

  {
    const u16* src = wg + (size_t)srow*2240 + sseg;
    *(uint4*)&s_b[0][srow*72 + sseg]     = *(const uint4*)src;
    *(uint4*)&s_b[0][srow*72 + sseg + 8] = *(const uint4*)(src + 8);
  }
  bf16x8 aC0 = *(const bf16x8*)(ap);
  bf16x8 aC1 = *(const bf16x8*)(ap + 32);
  bf16x8 aN0 = *(const bf16x8*)(ap + 64);
  bf16x8 aN1 = *(const bf16x8*)(ap + 96);
  f32x4 acc[4];
  #pragma unroll
  for (int q = 0; q < 4; q++) acc[q] = (f32x4){0.f,0.f,0.f,0.f};
  __syncthreads();

  for (int kp = 0; kp < 35; kp++) {
    uint4 b0v, b1v;
    if (kp < 34) {
      const u16* src = wg + (size_t)srow*2240 + (kp+1)*64 + sseg;
      b0v = *(const uint4*)src;
      b1v = *(const uint4*)(src + 8);
    }
    bf16x8 aF0 = aN0, aF1 = aN1;
    if (kp < 33) {
      aF0 = *(const bf16x8*)(ap + (size_t)(kp+2)*64);
      aF1 = *(const bf16x8*)(ap + (size_t)(kp+2)*64 + 32);
    }
    const u16* sb = &s_b[kp & 1][0];
    #pragma unroll
    for (int q = 0; q < 4; q++) {
      bf16x8 bv0 = *(const bf16x8*)&sb[((wn*4 + q)*16 + arow)*72 + grp*8];
      acc[q] = __builtin_amdgcn_mfma_f32_16x16x32_bf16(aC0, bv0, acc[q], 0, 0, 0);
    }
    #pragma unroll
    for (int q = 0; q < 4; q++) {
      bf16x8 bv1 = *(const bf16x8*)&sb[((wn*4 + q)*16 + arow)*72 + 32 + grp*8];
      acc[q] = __builtin_amdgcn_mfma_f32_16x16x32_bf16(aC1, bv1, acc[q], 0, 0, 0);
    }
    if (kp < 34) {
      *(uint4*)&s_b[(kp+1) & 1][srow*72 + sseg]     = b0v;
      *(uint4*)&s_b[(kp+1) & 1][srow*72 + sseg + 8] = b1v;
    }
    aC0 = aN0; aC1 = aN1; aN0 = aF0; aN1 = aF1;
    bar_lds();
  }

  #pragma unroll
  for (int q = 0; q < 4; q++)
    #pragma unroll
    for (int r = 0; r < 4; r++)
      s_g[(wm*16 + grp*4 + r)*204 + (wn*4 + q)*16 + arow] = f2bf(fmaxf(acc[q][r] + gfbv[q], 0.f));
  {
    int row = tid >> 3, seg = (tid & 7) * 8;
    uint4 c0 = *(const uint4*)(ctxg + (size_t)(m0 + row)*64 + seg);
    *(uint4*)&s_g[row*204 + 128 + seg] = c0;
  }
  bar_lds();

  f32x4 tacc[4];
  #pragma unroll
  for (int q = 0; q < 4; q++) tacc[q] = (f32x4){0.f,0.f,0.f,0.f};
  #pragma unroll
  for (int ks = 0; ks < 6; ks++) {
    bf16x8 av = *(const bf16x8*)&s_g[(wm*16 + arow)*204 + ks*32 + grp*8];
    #pragma unroll
    for (int q = 0; q < 4; q++) {
      bf16x8 bv = *(const bf16x8*)(wsb + WT_OFF + (size_t)((wn*4 + q)*16 + arow)*192 + ks*32 + grp*8);
      tacc[q] = __builtin_amdgcn_mfma_f32_16x16x32_bf16(av, bv, tacc[q], 0, 0, 0);
    }
  }
  bar_lds();
  #pragma unroll
  for (int q = 0; q < 4; q++)
    #pragma unroll
    for (int r = 0; r < 4; r++)
      s_g[(wm*16 + grp*4 + r)*204 + (wn*4 + q)*16 + arow] = f2bf(fmaxf(tacc[q][r] + tbvv[q], 0.f));
  bar_lds();

  {
    const int t0 = (nbase + m0) & 127;
    const int bb = (nbase + m0) >> 7;
    int row = tid >> 3, seg = (tid & 7) * 16;
    #pragma unroll
    for (int j = 0; j < 2; j++) {
      uint4 v = *(const uint4*)&s_g[row*204 + seg + j*8];
      *(uint4*)(trunk_ws + ((size_t)(t0 + row)*B_ + bb)*128 + seg + j*8) = v;
    }
  }
}

// ---------------------------------------------------------------------------
// K2: MFMA LSTM v6 = v5 + in-kernel x-gates from trunk (R10 ring pattern).
// Per step: racc (h) + xB = X(t+1); gate totals = racc + xA summed BEFORE
// the single intra-wave shuffle redistribution. k_xg deleted.
// ---------------------------------------------------------------------------
__global__ __launch_bounds__(512, 1) void k_lstm(
    const u16* __restrict__ trunk_ws, const float* __restrict__ whh,
    const float* __restrict__ wih, const float* __restrict__ bih,
    u16* __restrict__ h_ws)
{
  __shared__ __align__(16) u16 s_h[2][16*136];   // rows 4..15 stay zero
  __shared__ __align__(16) u16 s_tk[3][4*136];   // trunk ring, 4-row slots

  const int tid  = threadIdx.x;
  const int lane = tid & 63;
  const int w    = tid >> 6;
  const int arow = lane & 15;
  const int grp  = lane >> 4;
  const int b0   = blockIdx.x * 4;

  bf16x8 Bv[4][4], Bw[4][4];
  float bihv[4];
  #pragma unroll
  for (int j = 0; j < 4; j++) {
    const int row = j*128 + w*16 + arow;
    bihv[j] = bih[row];
    #pragma unroll
    for (int ks = 0; ks < 4; ks++) {
      const float* s1 = whh + (size_t)row*128 + ks*32 + grp*8;
      const float* s2 = wih + (size_t)row*128 + ks*32 + grp*8;
      float4 a0 = *(const float4*)s1, a1 = *(const float4*)(s1 + 4);
      float4 b0v = *(const float4*)s2, b1v = *(const float4*)(s2 + 4);
      bf16x8 t1, t2;
      t1[0]=(short)f2bf(a0.x); t1[1]=(short)f2bf(a0.y); t1[2]=(short)f2bf(a0.z); t1[3]=(short)f2bf(a0.w);
      t1[4]=(short)f2bf(a1.x); t1[5]=(short)f2bf(a1.y); t1[6]=(short)f2bf(a1.z); t1[7]=(short)f2bf(a1.w);
      t2[0]=(short)f2bf(b0v.x); t2[1]=(short)f2bf(b0v.y); t2[2]=(short)f2bf(b0v.z); t2[3]=(short)f2bf(b0v.w);
      t2[4]=(short)f2bf(b1v.x); t2[5]=(short)f2bf(b1v.y); t2[6]=(short)f2bf(b1v.z); t2[7]=(short)f2bf(b1v.w);
      Bv[j][ks] = t1; Bw[j][ks] = t2;
    }
  }

  for (int i = tid; i < 2*16*136; i += 512) ((u16*)s_h)[i] = 0;

  const int prow = tid >> 4, pseg = (tid & 15) * 8;   // tid<64 cohorts
  if (tid < 64) {
    #pragma unroll
    for (int s = 0; s < 3; s++)
      *(uint4*)&s_tk[s][prow*136 + pseg] =
          *(const uint4*)(trunk_ws + ((size_t)s*B_ + b0 + prow)*128 + pseg);
  }
  uint4 P0 = {0,0,0,0};
  if (tid < 64)
    P0 = *(const uint4*)(trunk_ws + ((size_t)3*B_ + b0 + prow)*128 + pseg);

  float cst = 0.f;
  __syncthreads();

  // xA = X(0) from slot 0
  f32x4 xA[4];
  #pragma unroll
  for (int j = 0; j < 4; j++) xA[j] = (f32x4){0.f,0.f,0.f,0.f};
  #pragma unroll
  for (int ks = 0; ks < 4; ks++) {
    bf16x8 av = *(const bf16x8*)&s_tk[0][(arow & 3)*136 + ks*32 + grp*8];
    #pragma unroll
    for (int j = 0; j < 4; j++)
      xA[j] = __builtin_amdgcn_mfma_f32_16x16x32_bf16(av, Bw[j][ks], xA[j], 0, 0, 0);
  }

  for (int t = 0; t < T_; t++) {
    const int p = t & 1;

    // issue tile t+4 (parked NEXT step)
    uint4 P1 = {0,0,0,0};
    if ((t + 4 < T_) && tid < 64)
      P1 = *(const uint4*)(trunk_ws + ((size_t)(t+4)*B_ + b0 + prow)*128 + pseg);

    // coalesced copy-out h(t-1)
    if (t > 0 && tid < 64) {
      uint4 hv = *(const uint4*)&s_h[p][prow*136 + pseg];
      *(uint4*)(h_ws + ((size_t)(t-1)*B_ + b0 + prow)*128 + pseg) = hv;
    }

    // recurrent MFMA + xB = X(t+1)  (same operand order -> same D layout)
    f32x4 racc[4], xB[4];
    #pragma unroll
    for (int j = 0; j < 4; j++) { racc[j] = (f32x4){0.f,0.f,0.f,0.f}; xB[j] = (f32x4){0.f,0.f,0.f,0.f}; }
    #pragma unroll
    for (int ks = 0; ks < 4; ks++) {
      bf16x8 av = *(const bf16x8*)&s_h[p][arow*136 + ks*32 + grp*8];
      #pragma unroll
      for (int j = 0; j < 4; j++)
        racc[j] = __builtin_amdgcn_mfma_f32_16x16x32_bf16(av, Bv[j][ks], racc[j], 0, 0, 0);
    }
    {
      const u16* tk = &s_tk[(t+1) % 3][0];
      #pragma unroll
      for (int ks = 0; ks < 4; ks++) {
        bf16x8 av = *(const bf16x8*)&tk[(arow & 3)*136 + ks*32 + grp*8];
        #pragma unroll
        for (int j = 0; j < 4; j++)
          xB[j] = __builtin_amdgcn_mfma_f32_16x16x32_bf16(av, Bw[j][ks], xB[j], 0, 0, 0);
      }
    }

    // g_total = racc + xA, one shuffle set
    float g4[4];
    #pragma unroll
    for (int j = 0; j < 4; j++) {
      float s0 = racc[j][0] + xA[j][0];
      float s1 = racc[j][1] + xA[j][1];
      float s2 = racc[j][2] + xA[j][2];
      float s3 = racc[j][3] + xA[j][3];
      float t0v = __shfl(s0, arow);
      float t1v = __shfl(s1, arow);
      float t2v = __shfl(s2, arow);
      float t3v = __shfl(s3, arow);
      g4[j] = (grp == 0) ? t0v : (grp == 1) ? t1v : (grp == 2) ? t2v : t3v;
    }

    {
      float xi = g4[0] + bihv[0];
      float xf = g4[1] + bihv[1];
      float xg = g4[2] + bihv[2];
      float xo = g4[3] + bihv[3];
      float I = sigm(xi), F = sigm(xf), O = sigm(xo), G = tanh_f(xg);
      cst = F*cst + I*G;
      float hvv = O * tanh_f(cst);
      s_h[1-p][grp*136 + w*16 + arow] = f2bf(hvv);
    }

    // park P0 (tile t+3, issued LAST step) into slot t%3
    if ((t + 3 < T_) && tid < 64)
      *(uint4*)&s_tk[t % 3][prow*136 + pseg] = P0;
    P0 = P1;
    #pragma unroll
    for (int j = 0; j < 4; j++) xA[j] = xB[j];
    bar_lds();
  }

  if (tid < 64) {
    uint4 hv = *(const uint4*)&s_h[T_ & 1][prow*136 + pseg];
    *(uint4*)(h_ws + ((size_t)(T_-1)*B_ + b0 + prow)*128 + pseg) = hv;
  }
}

// ---------------------------------------------------------------------------
// K3: heads (verbatim).
// ---------------------------------------------------------------------------
__global__ __launch_bounds__(256, 1) void k_heads(
    const u16* __restrict__ h_ws, const int* __restrict__ actions,
    const float* __restrict__ aw, const float* __restrict__ ab,
    const float* __restrict__ cw, const float* __restrict__ cb,
    float* __restrict__ out)
{
  const int tid  = threadIdx.x;
  const int lane = tid & 63;
  const int w    = tid >> 6;
  const int arow = lane & 15;
  const int grp  = lane >> 4;

  bf16x8 Ah[4];
  #pragma unroll
  for (int ks = 0; ks < 4; ks++) {
    bf16x8 v = {0,0,0,0,0,0,0,0};
    if (arow < 4) {
      const float* src = aw + arow*128 + ks*32 + grp*8;
      #pragma unroll
      for (int j = 0; j < 8; j++) v[j] = (short)f2bf(src[j]);
    } else if (arow == 4) {
      const float* src = cw + ks*32 + grp*8;
      #pragma unroll
      for (int j = 0; j < 8; j++) v[j] = (short)f2bf(src[j]);
    }
    Ah[ks] = v;
  }
  const float ab0=ab[0], ab1=ab[1], ab2=ab[2], ab3=ab[3], cb0=cb[0];

  #pragma unroll
  for (int g = 0; g < 4; g++) {
    int m0 = (blockIdx.x*4 + w)*64 + g*16;
    int t  = m0 >> 10; int bb = m0 & 1023;
    f32x4 acc = {0.f,0.f,0.f,0.f};
    #pragma unroll
    for (int ks = 0; ks < 4; ks++) {
      bf16x8 bv = *(const bf16x8*)(h_ws + ((size_t)t*B_ + bb + arow)*128 + ks*32 + grp*8);
      acc = __builtin_amdgcn_mfma_f32_16x16x32_bf16(Ah[ks], bv, acc, 0, 0, 0);
    }
    float cr = __shfl_xor(acc[0], 16);
    if (grp == 0) {
      float L0 = acc[0] + ab0, L1 = acc[1] + ab1, L2 = acc[2] + ab2, L3 = acc[3] + ab3;
      float Lv = cr + cb0;
      float mm = fmaxf(fmaxf(L0, L1), fmaxf(L2, L3));
      float e0 = __expf(L0-mm), e1 = __expf(L1-mm), e2 = __expf(L2-mm), e3 = __expf(L3-mm);
      float S = e0+e1+e2+e3; float lse = __logf(S);
      float p0=L0-mm-lse, p1=L1-mm-lse, p2=L2-mm-lse, p3=L3-mm-lse;
      int n = (bb + arow)*T_ + t;
      int a = actions[n];
      float lpa = (a==0)?p0:(a==1)?p1:(a==2)?p2:p3;
      float ent = -(e0*p0 + e1*p1 + e2*p2 + e3*p3) / S;
      out[n] = lpa; out[NBT + n] = Lv; out[2*NBT + n] = ent;
    }
  }
}

extern "C" void kernel_launch(void* const* d_in, const int* in_sizes, int n_in,
                              void* d_out, int out_size, void* d_ws, size_t ws_size,
                              hipStream_t stream) {
  const float* states = (const float*)d_in[0];
  const int*   actions= (const int*)  d_in[1];
  const float* c1w = (const float*)d_in[2];
  const float* c1b = (const float*)d_in[3];
  const float* c2w = (const float*)d_in[4];
  const float* c2b = (const float*)d_in[5];
  const float* gfw = (const float*)d_in[6];
  const float* gfb = (const float*)d_in[7];
  const float* cfw = (const float*)d_in[8];
  const float* cfb = (const float*)d_in[9];
  const float* tw  = (const float*)d_in[10];
  const float* tbv = (const float*)d_in[11];
  const float* wih = (const float*)d_in[12];
  const float* bih = (const float*)d_in[13];
  const float* whh = (const float*)d_in[14];
  const float* aw  = (const float*)d_in[15];
  const float* ab  = (const float*)d_in[16];
  const float* cw  = (const float*)d_in[17];
  const float* cb  = (const float*)d_in[18];
  float* out = (float*)d_out;

  u16* wsb   = (u16*)d_ws;
  u16* trunk = (u16*)((char*)d_ws + TRUNK_OFF);
  u16* h_ws  = (u16*)((char*)d_ws + H_OFF);
  u16* ctxg  = (u16*)((char*)d_ws + CTX_OFF);
  u16* c2g   = (u16*)((char*)d_ws + C2_OFF);

  k_cvt<<<(CVT_TOTAL + 255)/256, 256, 0, stream>>>(gfw, tw, wih, c2w, c1w, wsb);

  for (int c = 0; c < NCHUNK; c++) {
    const float* st_c = states + (size_t)c * CHUNK * 94;
    u16* ctx_c = ctxg + (size_t)c * CHUNK * 64;
    k_conv<<<CHUNK/64, 512, 0, stream>>>(st_c, c1b, c2b, cfw, cfb, wsb, c2g, ctx_c);
    k_gemm<<<CHUNK/64, 512, 0, stream>>>(c2g, ctx_c, gfb, tbv, wsb, trunk, c*CHUNK);
  }
  k_lstm<<<B_/4, 512, 0, stream>>>(trunk, whh, wih, bih, h_ws);
  k_heads<<<512, 256, 0, stream>>>(h_ws, actions, aw, ab, cw, cb, out);
}